// Round 1
// 850.013 us; speedup vs baseline: 1.1483x; 1.1483x over previous
//
#include <hip/hip_runtime.h>

#define NN 8192
#define EE 524288
#define HPAD 256   // hidden 200 padded to 256
#define NP 640     // 3*200 output cols padded to 640 (5 x 128 tiles)

using s16x8 = __attribute__((ext_vector_type(8))) short;
using f32x4 = __attribute__((ext_vector_type(4))) float;

__device__ __forceinline__ unsigned short f2b(float f) {
    unsigned u = __float_as_uint(f);
    u = (u + 0x7FFFu + ((u >> 16) & 1u)) >> 16;   // round-to-nearest-even
    return (unsigned short)u;
}
__device__ __forceinline__ float b2f(unsigned short u) {
    return __uint_as_float((unsigned)u << 16);
}

// async 16B global->LDS (direct DMA). Dest is wave-uniform base + lane*16.
__device__ __forceinline__ void async16(const unsigned short* g, unsigned short* l)
{
    __builtin_amdgcn_global_load_lds(
        (const __attribute__((address_space(1))) unsigned int*)g,
        (__attribute__((address_space(3))) unsigned int*)l, 16, 0, 0);
}

// ---------------- conversions ----------------

__global__ void cvt_f2b_kernel(const float* __restrict__ in,
                               unsigned short* __restrict__ out, int n4)
{
    int i = blockIdx.x * 256 + threadIdx.x;
    if (i >= n4) return;
    float4 v = ((const float4*)in)[i];
    ushort4 o;
    o.x = f2b(v.x); o.y = f2b(v.y); o.z = f2b(v.z); o.w = f2b(v.w);
    ((ushort4*)out)[i] = o;
}

// out[n][k] (bf16, [Nout, Kout]) = concat(w0|w1|w2)[k][n], zero-padded.
__global__ void transpose_w_kernel(const float* __restrict__ w0,
                                   const float* __restrict__ w1,
                                   const float* __restrict__ w2,
                                   unsigned short* __restrict__ out,
                                   int Kout, int Kreal, int Nreal)
{
    __shared__ float tile[32][33];
    const int kb = blockIdx.x << 5;
    const int nb = blockIdx.y << 5;
    const int tx = threadIdx.x, ty = threadIdx.y;   // 32 x 8
    const int n = nb + tx;
    const float* w = (n < 200) ? w0 : (n < 400) ? w1 : w2;
    const int c = (n < 200) ? n : (n < 400) ? n - 200 : n - 400;
#pragma unroll
    for (int i = 0; i < 4; ++i) {
        const int k = kb + ty + (i << 3);
        float v = 0.f;
        if (n < Nreal && k < Kreal) v = w[(size_t)k * 200 + c];
        tile[ty + (i << 3)][tx] = v;
    }
    __syncthreads();
#pragma unroll
    for (int i = 0; i < 4; ++i) {
        const int nn = nb + ty + (i << 3);
        out[(size_t)nn * Kout + kb + tx] = f2b(tile[tx][ty + (i << 3)]);
    }
}

// ---------------- MFMA GEMM: dbuf LDS + async DMA, 1 barrier per K-step ------
// C_plane[z][8192, ldc] = A[:, z*KC:(z+1)*KC] @ BT[:, z*KC:(z+1)*KC]^T
// LDS layout: slot s of row r holds k-chunk s^(r&7)  (conflict-free ds_read).
// XCD-chunked swizzle (T1): the nx col-tiles of one row-strip share an A panel;
// mapping consecutive original tiles to the SAME XCD turns the 5x A re-read
// (672 MB from L3) into per-XCD L2 hits. nwg per plane is a multiple of 8.
__global__ __launch_bounds__(256) void gemm_mfma(
    const unsigned short* __restrict__ A,
    const unsigned short* __restrict__ BT,
    float* __restrict__ C, unsigned short* __restrict__ Cb,
    int lda, int KC, int ldc, size_t planeStride)
{
    __shared__ unsigned short As[2][128 * 64];
    __shared__ unsigned short Bs[2][128 * 64];
    const int tid  = threadIdx.x;
    const int lane = tid & 63;
    const int w    = tid >> 6;

    // XCD-aware remap (bijective; nwg % 8 == 0 for all our launches)
    const int nx   = gridDim.x;
    const int flat = blockIdx.y * nx + blockIdx.x;
    const int cpx  = (nx * gridDim.y) >> 3;
    const int orig = (flat & 7) * cpx + (flat >> 3);
    const int by   = orig / nx;
    const int bx   = orig - by * nx;

    const int row0 = by << 7;
    const int col0 = bx << 7;
    const int z    = blockIdx.z;
    const int wm = (w >> 1) << 6;
    const int wn = (w & 1) << 6;

    const int sr = lane >> 3;             // row within wave's 8-row strip
    const int sc = (lane & 7) ^ sr;       // global chunk to fetch (xor-permuted)
    const size_t kbase = (size_t)z * KC + ((size_t)sc << 3);
    const unsigned short* aG = A  + (size_t)(row0 + w * 8 + sr) * lda + kbase;
    const unsigned short* bG = BT + (size_t)(col0 + w * 8 + sr) * lda + kbase;
    const int ldsOff = w * 8;             // wave's strip base row

    const f32x4 zero = {0.f, 0.f, 0.f, 0.f};
    f32x4 acc[4][4];
#pragma unroll
    for (int i = 0; i < 4; ++i)
#pragma unroll
        for (int j = 0; j < 4; ++j) acc[i][j] = zero;

    // stage tile 0 into buf 0
#pragma unroll
    for (int it = 0; it < 4; ++it) {
        async16(aG + (size_t)(it * 32) * lda, &As[0][(it * 32 + ldsOff) << 6]);
        async16(bG + (size_t)(it * 32) * lda, &Bs[0][(it * 32 + ldsOff) << 6]);
    }
    __syncthreads();

    const int T = KC >> 6;
    for (int t = 0; t < T; ++t) {
        const int cur = t & 1;
        if (t + 1 < T) {
            const int ko = (t + 1) << 6;
#pragma unroll
            for (int it = 0; it < 4; ++it) {
                async16(aG + (size_t)(it * 32) * lda + ko,
                        &As[cur ^ 1][(it * 32 + ldsOff) << 6]);
                async16(bG + (size_t)(it * 32) * lda + ko,
                        &Bs[cur ^ 1][(it * 32 + ldsOff) << 6]);
            }
        }
#pragma unroll
        for (int kk = 0; kk < 2; ++kk) {
            const int q  = (kk << 2) + (lane >> 4);
            const int sl = (q ^ (lane & 7)) << 3;
            s16x8 af[4], bfv[4];
#pragma unroll
            for (int i = 0; i < 4; ++i) {
                const int rm = wm + (i << 4) + (lane & 15);
                af[i]  = *(const s16x8*)(&As[cur][(rm << 6) + sl]);
                const int rn = wn + (i << 4) + (lane & 15);
                bfv[i] = *(const s16x8*)(&Bs[cur][(rn << 6) + sl]);
            }
#pragma unroll
            for (int i = 0; i < 4; ++i)
#pragma unroll
                for (int j = 0; j < 4; ++j)
                    acc[i][j] = __builtin_amdgcn_mfma_f32_16x16x32_bf16(
                        af[i], bfv[j], acc[i][j], 0, 0, 0);
        }
        __syncthreads();   // drains this iter's DMA; protects buf swap
    }

    const int cr = (lane >> 4) << 2;      // C/D: row = quad*4 + r, col = lane&15
    const int cc = lane & 15;
    if (Cb) {
#pragma unroll
        for (int i = 0; i < 4; ++i)
#pragma unroll
            for (int j = 0; j < 4; ++j)
#pragma unroll
                for (int r = 0; r < 4; ++r)
                    Cb[(size_t)(row0 + wm + (i << 4) + cr + r) * ldc
                       + (col0 + wn + (j << 4) + cc)] = f2b(acc[i][j][r]);
    } else {
        float* Cp = C + (size_t)z * planeStride;
#pragma unroll
        for (int i = 0; i < 4; ++i)
#pragma unroll
            for (int j = 0; j < 4; ++j)
#pragma unroll
                for (int r = 0; r < 4; ++r)
                    Cp[(size_t)(row0 + wm + (i << 4) + cr + r) * ldc
                       + (col0 + wn + (j << 4) + cc)] = acc[i][j][r];
    }
}

// ---------------- combine: fp32 self + two contiguous bf16 message arrays ----
// y_simb / y_ratb: [8192,200] bf16 (3.28 MB each -> L2/L3 resident)
__global__ void combine_kernel(const float* __restrict__ p0,
                               const float* __restrict__ p1,
                               float* __restrict__ y_self,
                               unsigned short* __restrict__ y_simb,
                               unsigned short* __restrict__ y_ratb)
{
    int t = blockIdx.x * 256 + threadIdx.x;    // n*50 + j4chunk
    int n = t / 50, j4 = (t - n * 50) << 2;
    const float* a = p0 + (size_t)n * NP;
    float4 s = *(const float4*)(a + j4);
    float4 m = *(const float4*)(a + 200 + j4);
    float4 r = *(const float4*)(a + 400 + j4);
    if (p1) {
        const float* b = p1 + (size_t)n * NP;
        float4 s2 = *(const float4*)(b + j4);
        float4 m2 = *(const float4*)(b + 200 + j4);
        float4 r2 = *(const float4*)(b + 400 + j4);
        s.x += s2.x; s.y += s2.y; s.z += s2.z; s.w += s2.w;
        m.x += m2.x; m.y += m2.y; m.z += m2.z; m.w += m2.w;
        r.x += r2.x; r.y += r2.y; r.z += r2.z; r.w += r2.w;
    }
    *(float4*)(y_self + (size_t)n * 200 + j4) = s;
    ushort4 mo, ro;
    mo.x = f2b(m.x); mo.y = f2b(m.y); mo.z = f2b(m.z); mo.w = f2b(m.w);
    ro.x = f2b(r.x); ro.y = f2b(r.y); ro.z = f2b(r.z); ro.w = f2b(r.w);
    *(ushort4*)(y_simb + (size_t)n * 200 + j4) = mo;
    *(ushort4*)(y_ratb + (size_t)n * 200 + j4) = ro;
}

// ---------------- edge sort (counting sort by dst, payload = (src, eid)) -----
// Batched: blockIdx.y (hist/reorder) or blockIdx.x (scan) picks the edge type.

__global__ void hist_kernel(const int* __restrict__ e0, const int* __restrict__ e1,
                            int* __restrict__ d0, int* __restrict__ d1)
{
    const int* edges = blockIdx.y ? e1 : e0;
    int* deg = blockIdx.y ? d1 : d0;
    int e = blockIdx.x * 256 + threadIdx.x;
    if (e < EE) atomicAdd(&deg[edges[EE + e]], 1);
}

__global__ void scan_kernel(const int* __restrict__ deg0, int* __restrict__ off0,
                            int* __restrict__ pos0,
                            const int* __restrict__ deg1, int* __restrict__ off1,
                            int* __restrict__ pos1)
{
    const int* deg = blockIdx.x ? deg1 : deg0;
    int* off = blockIdx.x ? off1 : off0;
    int* pos = blockIdx.x ? pos1 : pos0;
    __shared__ int part[256];
    const int t = threadIdx.x;
    const int base = t * 32;
    int s = 0;
#pragma unroll
    for (int i = 0; i < 32; ++i) s += deg[base + i];
    part[t] = s;
    __syncthreads();
    for (int d = 1; d < 256; d <<= 1) {
        int v = (t >= d) ? part[t - d] : 0;
        __syncthreads();
        part[t] += v;
        __syncthreads();
    }
    int run = (t == 0) ? 0 : part[t - 1];
    for (int i = 0; i < 32; ++i) {
        off[base + i] = run;
        pos[base + i] = run;
        run += deg[base + i];
    }
    if (t == 255) off[NN] = run;
}

__global__ void reorder_kernel(const int* __restrict__ e0, int* __restrict__ pos0,
                               int2* __restrict__ se0,
                               const int* __restrict__ e1, int* __restrict__ pos1,
                               int2* __restrict__ se1)
{
    const int* edges = blockIdx.y ? e1 : e0;
    int* pos = blockIdx.y ? pos1 : pos0;
    int2* se = blockIdx.y ? se1 : se0;
    int e = blockIdx.x * 256 + threadIdx.x;
    if (e >= EE) return;
    int p = atomicAdd(&pos[edges[EE + e]], 1);
    se[p] = make_int2(edges[e], e);
}

// ---------------- fused aggregation --------------------------------------
// One kernel per layer: acc = sum_sim + sum_rat (two edge loops, 4-way
// unrolled to break the se->gather dependent-latency chain), then
// hb = bf16(relu?(y_self + bias + acc)), padded to HPAD.

__device__ __forceinline__ void edge_accum(
    const unsigned short* __restrict__ msg,
    const int* __restrict__ off, const int2* __restrict__ se,
    int n, int w, int j4, bool act, float4& acc)
{
    const int e1 = off[n + 1];
    int i = off[n] + w;
    // 4 independent se loads, then 4 independent gathers: latency amortized 4x
    for (; i + 12 < e1; i += 16) {
        const int s0 = se[i].x;
        const int s1 = se[i + 4].x;
        const int s2 = se[i + 8].x;
        const int s3 = se[i + 12].x;
        if (act) {
            ushort4 v0 = *(const ushort4*)(msg + (size_t)s0 * 200 + j4);
            ushort4 v1 = *(const ushort4*)(msg + (size_t)s1 * 200 + j4);
            ushort4 v2 = *(const ushort4*)(msg + (size_t)s2 * 200 + j4);
            ushort4 v3 = *(const ushort4*)(msg + (size_t)s3 * 200 + j4);
            acc.x += (b2f(v0.x) + b2f(v1.x)) + (b2f(v2.x) + b2f(v3.x));
            acc.y += (b2f(v0.y) + b2f(v1.y)) + (b2f(v2.y) + b2f(v3.y));
            acc.z += (b2f(v0.z) + b2f(v1.z)) + (b2f(v2.z) + b2f(v3.z));
            acc.w += (b2f(v0.w) + b2f(v1.w)) + (b2f(v2.w) + b2f(v3.w));
        }
    }
    for (; i < e1; i += 4) {
        const int s = se[i].x;
        if (act) {
            ushort4 v = *(const ushort4*)(msg + (size_t)s * 200 + j4);
            acc.x += b2f(v.x); acc.y += b2f(v.y);
            acc.z += b2f(v.z); acc.w += b2f(v.w);
        }
    }
}

__global__ __launch_bounds__(256) void agg_fused_kernel(
    const unsigned short* __restrict__ msg_sim,
    const unsigned short* __restrict__ msg_rat,
    const int* __restrict__ off_sim, const int2* __restrict__ se_sim,
    const int* __restrict__ off_rat, const int2* __restrict__ se_rat,
    const float* __restrict__ y_self, const float* __restrict__ bias,
    unsigned short* __restrict__ hb, int relu)
{
    __shared__ float part[4][200];
    const int n = blockIdx.x;
    const int w = threadIdx.x >> 6;
    const int lane = threadIdx.x & 63;
    const int j4 = lane << 2;
    const bool act = lane < 50;

    float4 acc = {0.f, 0.f, 0.f, 0.f};
    edge_accum(msg_sim, off_sim, se_sim, n, w, j4, act, acc);
    edge_accum(msg_rat, off_rat, se_rat, n, w, j4, act, acc);

    if (act) *(float4*)&part[w][j4] = acc;
    __syncthreads();
    const int j = threadIdx.x;
    if (j < 200) {
        float v = part[0][j] + part[1][j] + part[2][j] + part[3][j]
                + y_self[(size_t)n * 200 + j] + bias[j];
        if (relu) v = fmaxf(v, 0.f);
        hb[((size_t)n << 8) + j] = f2b(v);
    } else if (j < HPAD) {
        hb[((size_t)n << 8) + j] = 0;     // zero the pad (ws is poisoned)
    }
}

// ---------------- decoder: dst-grouped, hQ gathered from L2-resident array ---
__global__ __launch_bounds__(256) void pred_kernel(
    const unsigned short* __restrict__ hQb,  // [8192, HPAD] bf16
    const unsigned short* __restrict__ h2b,  // [8192, HPAD] bf16
    const int* __restrict__ off, const int2* __restrict__ se,
    const int* __restrict__ mask, float* __restrict__ out)
{
    const int n = blockIdx.x;
    const int w = threadIdx.x >> 6;
    const int lane = threadIdx.x & 63;
    float4 b = {0.f, 0.f, 0.f, 0.f};
    if (lane < 50) {
        ushort4 v = *(const ushort4*)(h2b + ((size_t)n << 8) + (lane << 2));
        b.x = b2f(v.x); b.y = b2f(v.y); b.z = b2f(v.z); b.w = b2f(v.w);
    }
    const int e1 = off[n + 1];
    int i = off[n] + w;
    for (; i + 12 < e1; i += 16) {
        const int2 p0 = se[i];
        const int2 p1 = se[i + 4];
        const int2 p2 = se[i + 8];
        const int2 p3 = se[i + 12];
        float s0 = 0.f, s1 = 0.f, s2 = 0.f, s3 = 0.f;
        if (lane < 50) {
            ushort4 a0 = *(const ushort4*)(hQb + ((size_t)p0.x << 8) + (lane << 2));
            ushort4 a1 = *(const ushort4*)(hQb + ((size_t)p1.x << 8) + (lane << 2));
            ushort4 a2 = *(const ushort4*)(hQb + ((size_t)p2.x << 8) + (lane << 2));
            ushort4 a3 = *(const ushort4*)(hQb + ((size_t)p3.x << 8) + (lane << 2));
            s0 = fmaf(b2f(a0.x), b.x, fmaf(b2f(a0.y), b.y,
                 fmaf(b2f(a0.z), b.z, b2f(a0.w) * b.w)));
            s1 = fmaf(b2f(a1.x), b.x, fmaf(b2f(a1.y), b.y,
                 fmaf(b2f(a1.z), b.z, b2f(a1.w) * b.w)));
            s2 = fmaf(b2f(a2.x), b.x, fmaf(b2f(a2.y), b.y,
                 fmaf(b2f(a2.z), b.z, b2f(a2.w) * b.w)));
            s3 = fmaf(b2f(a3.x), b.x, fmaf(b2f(a3.y), b.y,
                 fmaf(b2f(a3.z), b.z, b2f(a3.w) * b.w)));
        }
#pragma unroll
        for (int o = 32; o > 0; o >>= 1) {    // 4 independent reduce chains
            s0 += __shfl_down(s0, o, 64);
            s1 += __shfl_down(s1, o, 64);
            s2 += __shfl_down(s2, o, 64);
            s3 += __shfl_down(s3, o, 64);
        }
        if (lane == 0) {
            out[p0.y] = mask[p0.y] ? (s0 + 3.5f) : 0.f;
            out[p1.y] = mask[p1.y] ? (s1 + 3.5f) : 0.f;
            out[p2.y] = mask[p2.y] ? (s2 + 3.5f) : 0.f;
            out[p3.y] = mask[p3.y] ? (s3 + 3.5f) : 0.f;
        }
    }
    for (; i < e1; i += 4) {
        const int2 p = se[i];
        float s = 0.f;
        if (lane < 50) {
            ushort4 a = *(const ushort4*)(hQb + ((size_t)p.x << 8) + (lane << 2));
            s = fmaf(b2f(a.x), b.x, fmaf(b2f(a.y), b.y,
                fmaf(b2f(a.z), b.z, b2f(a.w) * b.w)));
        }
#pragma unroll
        for (int o = 32; o > 0; o >>= 1) s += __shfl_down(s, o, 64);
        if (lane == 0) out[p.y] = mask[p.y] ? (s + 3.5f) : 0.f;
    }
}

// ---------------- launch ----------------
extern "C" void kernel_launch(void* const* d_in, const int* in_sizes, int n_in,
                              void* d_out, int out_size, void* d_ws, size_t ws_size,
                              hipStream_t stream)
{
    const float* x       = (const float*)d_in[0];
    const int*   e_sim   = (const int*)d_in[1];
    const int*   e_rat   = (const int*)d_in[2];
    const int*   mask    = (const int*)d_in[3];
    const float* w1_self = (const float*)d_in[4];
    const float* w1_sim  = (const float*)d_in[5];
    const float* w1_rat  = (const float*)d_in[6];
    const float* b1      = (const float*)d_in[7];
    const float* w2_self = (const float*)d_in[8];
    const float* w2_sim  = (const float*)d_in[9];
    const float* w2_rat  = (const float*)d_in[10];
    const float* b2      = (const float*)d_in[11];
    const float* Q       = (const float*)d_in[12];
    float* out = (float*)d_out;

    char* p = (char*)d_ws;
    auto alloc = [&](size_t bytes) -> char* {
        char* r = p;
        p += (bytes + 255) & ~(size_t)255;
        return r;
    };
    unsigned short* xb    = (unsigned short*)alloc((size_t)NN * NN * 2);   // 134 MB
    unsigned short* wbT1  = (unsigned short*)alloc((size_t)NP * NN * 2);   // 10.5 MB
    unsigned short* wbT2  = (unsigned short*)alloc((size_t)NP * HPAD * 2);
    unsigned short* QT    = (unsigned short*)alloc((size_t)HPAD * HPAD * 2);
    float* ypart = (float*)alloc((size_t)2 * NN * NP * 4);                 // 42 MB
    float* y_self = (float*)alloc((size_t)NN * 200 * 4);                   // 6.6 MB
    unsigned short* y_simb = (unsigned short*)alloc((size_t)NN * 200 * 2); // 3.28 MB
    unsigned short* y_ratb = (unsigned short*)alloc((size_t)NN * 200 * 2); // 3.28 MB
    unsigned short* h1b = (unsigned short*)alloc((size_t)NN * HPAD * 2);
    unsigned short* h2b = (unsigned short*)alloc((size_t)NN * HPAD * 2);
    unsigned short* hQb = (unsigned short*)alloc((size_t)NN * HPAD * 2);
    int* deg_sim = (int*)alloc(NN * 4);
    int* deg_rat = (int*)alloc(NN * 4);
    int* off_sim = (int*)alloc((NN + 1) * 4);
    int* off_rat = (int*)alloc((NN + 1) * 4);
    int* pos_sim = (int*)alloc(NN * 4);
    int* pos_rat = (int*)alloc(NN * 4);
    int2* se_sim = (int2*)alloc((size_t)EE * 8);
    int2* se_rat = (int2*)alloc((size_t)EE * 8);

    const dim3 blk(256);
    const dim3 tblk(32, 8);

    // conversions
    cvt_f2b_kernel<<<(NN * NN / 4) / 256, blk, 0, stream>>>(x, xb, NN * NN / 4);
    transpose_w_kernel<<<dim3(NN / 32, NP / 32), tblk, 0, stream>>>(
        w1_self, w1_sim, w1_rat, wbT1, NN, NN, 600);
    transpose_w_kernel<<<dim3(HPAD / 32, NP / 32), tblk, 0, stream>>>(
        w2_self, w2_sim, w2_rat, wbT2, HPAD, 200, 600);
    transpose_w_kernel<<<dim3(HPAD / 32, HPAD / 32), tblk, 0, stream>>>(
        Q, Q, Q, QT, HPAD, 200, 200);

    // edge sorts (dst-grouped, payload (src,eid)), both types batched
    hipMemsetAsync(deg_sim, 0, 2 * NN * 4, stream);   // deg_sim+deg_rat contiguous
    hist_kernel<<<dim3(EE / 256, 2), blk, 0, stream>>>(e_sim, e_rat, deg_sim, deg_rat);
    scan_kernel<<<2, blk, 0, stream>>>(deg_sim, off_sim, pos_sim,
                                       deg_rat, off_rat, pos_rat);
    reorder_kernel<<<dim3(EE / 256, 2), blk, 0, stream>>>(
        e_sim, pos_sim, se_sim, e_rat, pos_rat, se_rat);

    // layer 1 (split-K = 2)
    gemm_mfma<<<dim3(NP / 128, NN / 128, 2), blk, 0, stream>>>(
        xb, wbT1, ypart, nullptr, NN, NN / 2, NP, (size_t)NN * NP);
    combine_kernel<<<NN * 50 / 256, blk, 0, stream>>>(
        ypart, ypart + (size_t)NN * NP, y_self, y_simb, y_ratb);
    agg_fused_kernel<<<NN, blk, 0, stream>>>(
        y_simb, y_ratb, off_sim, se_sim, off_rat, se_rat, y_self, b1, h1b, 1);

    // layer 2
    gemm_mfma<<<dim3(NP / 128, NN / 128, 1), blk, 0, stream>>>(
        h1b, wbT2, ypart, nullptr, HPAD, HPAD, NP, 0);
    combine_kernel<<<NN * 50 / 256, blk, 0, stream>>>(
        ypart, nullptr, y_self, y_simb, y_ratb);
    agg_fused_kernel<<<NN, blk, 0, stream>>>(
        y_simb, y_ratb, off_sim, se_sim, off_rat, se_rat, y_self, b2, h2b, 0);

    // decoder (GEMM emits bf16 directly into hQb)
    gemm_mfma<<<dim3(HPAD / 128, NN / 128, 1), blk, 0, stream>>>(
        h2b, QT, nullptr, hQb, HPAD, HPAD, HPAD, 0);
    pred_kernel<<<NN, blk, 0, stream>>>(hQb, h2b, off_rat, se_rat, mask, out);
}

// Round 2
// 836.346 us; speedup vs baseline: 1.1671x; 1.0163x over previous
//
#include <hip/hip_runtime.h>

#define NN 8192
#define EE 524288
#define HPAD 256   // hidden 200 padded to 256
#define NP 640     // 3*200 output cols padded to 640 (5 x 128 tiles)

using s16x8 = __attribute__((ext_vector_type(8))) short;
using f32x4 = __attribute__((ext_vector_type(4))) float;

__device__ __forceinline__ unsigned short f2b(float f) {
    unsigned u = __float_as_uint(f);
    u = (u + 0x7FFFu + ((u >> 16) & 1u)) >> 16;   // round-to-nearest-even
    return (unsigned short)u;
}
__device__ __forceinline__ float b2f(unsigned short u) {
    return __uint_as_float((unsigned)u << 16);
}

// async 16B global->LDS (direct DMA). Dest is wave-uniform base + lane*16.
__device__ __forceinline__ void async16(const unsigned short* g, unsigned short* l)
{
    __builtin_amdgcn_global_load_lds(
        (const __attribute__((address_space(1))) unsigned int*)g,
        (__attribute__((address_space(3))) unsigned int*)l, 16, 0, 0);
}

// ---------------- conversions ----------------

__global__ void cvt_f2b_kernel(const float* __restrict__ in,
                               unsigned short* __restrict__ out, int n4)
{
    int i = blockIdx.x * 256 + threadIdx.x;
    if (i >= n4) return;
    float4 v = ((const float4*)in)[i];
    ushort4 o;
    o.x = f2b(v.x); o.y = f2b(v.y); o.z = f2b(v.z); o.w = f2b(v.w);
    ((ushort4*)out)[i] = o;
}

// out[n][k] (bf16, [Nout, Kout]) = concat(w0|w1|w2)[k][n], zero-padded.
__global__ void transpose_w_kernel(const float* __restrict__ w0,
                                   const float* __restrict__ w1,
                                   const float* __restrict__ w2,
                                   unsigned short* __restrict__ out,
                                   int Kout, int Kreal, int Nreal)
{
    __shared__ float tile[32][33];
    const int kb = blockIdx.x << 5;
    const int nb = blockIdx.y << 5;
    const int tx = threadIdx.x, ty = threadIdx.y;   // 32 x 8
    const int n = nb + tx;
    const float* w = (n < 200) ? w0 : (n < 400) ? w1 : w2;
    const int c = (n < 200) ? n : (n < 400) ? n - 200 : n - 400;
#pragma unroll
    for (int i = 0; i < 4; ++i) {
        const int k = kb + ty + (i << 3);
        float v = 0.f;
        if (n < Nreal && k < Kreal) v = w[(size_t)k * 200 + c];
        tile[ty + (i << 3)][tx] = v;
    }
    __syncthreads();
#pragma unroll
    for (int i = 0; i < 4; ++i) {
        const int nn = nb + ty + (i << 3);
        out[(size_t)nn * Kout + kb + tx] = f2b(tile[tx][ty + (i << 3)]);
    }
}

// ---------------- MFMA GEMM: dbuf LDS + async DMA, 1 barrier per K-step ------
// C_plane[z][8192, ldc] = A[:, z*KC:(z+1)*KC] @ BT[:, z*KC:(z+1)*KC]^T
// LDS layout: slot s of row r holds k-chunk s^(r&7)  (conflict-free ds_read).
// XCD-chunked swizzle (T1): consecutive col-tiles of one row-strip land on the
// same XCD so the 5x A re-read comes from that XCD's L2, not L3/HBM.
// Epilogue modes: ysb!=null -> fused combine (y_self fp32 / y_simb / y_ratb),
//                 Cb!=null  -> bf16 C, else fp32 C plane write.
__global__ __launch_bounds__(256) void gemm_mfma(
    const unsigned short* __restrict__ A,
    const unsigned short* __restrict__ BT,
    float* __restrict__ C, unsigned short* __restrict__ Cb,
    int lda, int KC, int ldc, size_t planeStride,
    float* __restrict__ ys, unsigned short* __restrict__ ysb,
    unsigned short* __restrict__ yrb)
{
    __shared__ unsigned short As[2][128 * 64];
    __shared__ unsigned short Bs[2][128 * 64];
    const int tid  = threadIdx.x;
    const int lane = tid & 63;
    const int w    = tid >> 6;

    // XCD-aware remap (bijective; nwg % 8 == 0 for all our launches)
    const int nx   = gridDim.x;
    const int flat = blockIdx.y * nx + blockIdx.x;
    const int cpx  = (nx * gridDim.y) >> 3;
    const int orig = (flat & 7) * cpx + (flat >> 3);
    const int by   = orig / nx;
    const int bx   = orig - by * nx;

    const int row0 = by << 7;
    const int col0 = bx << 7;
    const int z    = blockIdx.z;
    const int wm = (w >> 1) << 6;
    const int wn = (w & 1) << 6;

    const int sr = lane >> 3;             // row within wave's 8-row strip
    const int sc = (lane & 7) ^ sr;       // global chunk to fetch (xor-permuted)
    const size_t kbase = (size_t)z * KC + ((size_t)sc << 3);
    const unsigned short* aG = A  + (size_t)(row0 + w * 8 + sr) * lda + kbase;
    const unsigned short* bG = BT + (size_t)(col0 + w * 8 + sr) * lda + kbase;
    const int ldsOff = w * 8;             // wave's strip base row

    const f32x4 zero = {0.f, 0.f, 0.f, 0.f};
    f32x4 acc[4][4];
#pragma unroll
    for (int i = 0; i < 4; ++i)
#pragma unroll
        for (int j = 0; j < 4; ++j) acc[i][j] = zero;

    // stage tile 0 into buf 0
#pragma unroll
    for (int it = 0; it < 4; ++it) {
        async16(aG + (size_t)(it * 32) * lda, &As[0][(it * 32 + ldsOff) << 6]);
        async16(bG + (size_t)(it * 32) * lda, &Bs[0][(it * 32 + ldsOff) << 6]);
    }
    __syncthreads();

    const int T = KC >> 6;
    for (int t = 0; t < T; ++t) {
        const int cur = t & 1;
        if (t + 1 < T) {
            const int ko = (t + 1) << 6;
#pragma unroll
            for (int it = 0; it < 4; ++it) {
                async16(aG + (size_t)(it * 32) * lda + ko,
                        &As[cur ^ 1][(it * 32 + ldsOff) << 6]);
                async16(bG + (size_t)(it * 32) * lda + ko,
                        &Bs[cur ^ 1][(it * 32 + ldsOff) << 6]);
            }
        }
#pragma unroll
        for (int kk = 0; kk < 2; ++kk) {
            const int q  = (kk << 2) + (lane >> 4);
            const int sl = (q ^ (lane & 7)) << 3;
            s16x8 af[4], bfv[4];
#pragma unroll
            for (int i = 0; i < 4; ++i) {
                const int rm = wm + (i << 4) + (lane & 15);
                af[i]  = *(const s16x8*)(&As[cur][(rm << 6) + sl]);
                const int rn = wn + (i << 4) + (lane & 15);
                bfv[i] = *(const s16x8*)(&Bs[cur][(rn << 6) + sl]);
            }
#pragma unroll
            for (int i = 0; i < 4; ++i)
#pragma unroll
                for (int j = 0; j < 4; ++j)
                    acc[i][j] = __builtin_amdgcn_mfma_f32_16x16x32_bf16(
                        af[i], bfv[j], acc[i][j], 0, 0, 0);
        }
        __syncthreads();   // drains this iter's DMA; protects buf swap
    }

    const int cr = (lane >> 4) << 2;      // C/D: row = quad*4 + r, col = lane&15
    const int cc = lane & 15;
    if (ysb) {
        // fused combine epilogue (layer-2 GEMM, no split-K)
#pragma unroll
        for (int i = 0; i < 4; ++i)
#pragma unroll
            for (int j = 0; j < 4; ++j)
#pragma unroll
                for (int r = 0; r < 4; ++r) {
                    const int n = row0 + wm + (i << 4) + cr + r;
                    const int c = col0 + wn + (j << 4) + cc;
                    const float v = acc[i][j][r];
                    if (c < 200)      ys [(size_t)n * 200 + c]        = v;
                    else if (c < 400) ysb[(size_t)n * 200 + (c - 200)] = f2b(v);
                    else if (c < 600) yrb[(size_t)n * 200 + (c - 400)] = f2b(v);
                }
    } else if (Cb) {
#pragma unroll
        for (int i = 0; i < 4; ++i)
#pragma unroll
            for (int j = 0; j < 4; ++j)
#pragma unroll
                for (int r = 0; r < 4; ++r)
                    Cb[(size_t)(row0 + wm + (i << 4) + cr + r) * ldc
                       + (col0 + wn + (j << 4) + cc)] = f2b(acc[i][j][r]);
    } else {
        float* Cp = C + (size_t)z * planeStride;
#pragma unroll
        for (int i = 0; i < 4; ++i)
#pragma unroll
            for (int j = 0; j < 4; ++j)
#pragma unroll
                for (int r = 0; r < 4; ++r)
                    Cp[(size_t)(row0 + wm + (i << 4) + cr + r) * ldc
                       + (col0 + wn + (j << 4) + cc)] = acc[i][j][r];
    }
}

// ---------------- combine: sum nplanes fp32 partials -> self fp32 + 2x bf16 --
__global__ void combine_kernel(const float* __restrict__ parts, int nplanes,
                               float* __restrict__ y_self,
                               unsigned short* __restrict__ y_simb,
                               unsigned short* __restrict__ y_ratb)
{
    int t = blockIdx.x * 256 + threadIdx.x;    // n*50 + j4chunk
    int n = t / 50, j4 = (t - n * 50) << 2;
    float4 s = {0.f, 0.f, 0.f, 0.f};
    float4 m = {0.f, 0.f, 0.f, 0.f};
    float4 r = {0.f, 0.f, 0.f, 0.f};
    for (int z = 0; z < nplanes; ++z) {
        const float* a = parts + (size_t)z * NN * NP + (size_t)n * NP;
        float4 s2 = *(const float4*)(a + j4);
        float4 m2 = *(const float4*)(a + 200 + j4);
        float4 r2 = *(const float4*)(a + 400 + j4);
        s.x += s2.x; s.y += s2.y; s.z += s2.z; s.w += s2.w;
        m.x += m2.x; m.y += m2.y; m.z += m2.z; m.w += m2.w;
        r.x += r2.x; r.y += r2.y; r.z += r2.z; r.w += r2.w;
    }
    *(float4*)(y_self + (size_t)n * 200 + j4) = s;
    ushort4 mo, ro;
    mo.x = f2b(m.x); mo.y = f2b(m.y); mo.z = f2b(m.z); mo.w = f2b(m.w);
    ro.x = f2b(r.x); ro.y = f2b(r.y); ro.z = f2b(r.z); ro.w = f2b(r.w);
    *(ushort4*)(y_simb + (size_t)n * 200 + j4) = mo;
    *(ushort4*)(y_ratb + (size_t)n * 200 + j4) = ro;
}

// ---------------- edge sort (counting sort by dst, payload = (src, eid)) -----
// Batched: blockIdx.y (hist/reorder) or blockIdx.x (scan) picks the edge type.

__global__ void hist_kernel(const int* __restrict__ e0, const int* __restrict__ e1,
                            int* __restrict__ d0, int* __restrict__ d1)
{
    const int* edges = blockIdx.y ? e1 : e0;
    int* deg = blockIdx.y ? d1 : d0;
    int e = blockIdx.x * 256 + threadIdx.x;
    if (e < EE) atomicAdd(&deg[edges[EE + e]], 1);
}

__global__ void scan_kernel(const int* __restrict__ deg0, int* __restrict__ off0,
                            int* __restrict__ pos0,
                            const int* __restrict__ deg1, int* __restrict__ off1,
                            int* __restrict__ pos1)
{
    const int* deg = blockIdx.x ? deg1 : deg0;
    int* off = blockIdx.x ? off1 : off0;
    int* pos = blockIdx.x ? pos1 : pos0;
    __shared__ int part[256];
    const int t = threadIdx.x;
    const int base = t * 32;
    int s = 0;
#pragma unroll
    for (int i = 0; i < 32; ++i) s += deg[base + i];
    part[t] = s;
    __syncthreads();
    for (int d = 1; d < 256; d <<= 1) {
        int v = (t >= d) ? part[t - d] : 0;
        __syncthreads();
        part[t] += v;
        __syncthreads();
    }
    int run = (t == 0) ? 0 : part[t - 1];
    for (int i = 0; i < 32; ++i) {
        off[base + i] = run;
        pos[base + i] = run;
        run += deg[base + i];
    }
    if (t == 255) off[NN] = run;
}

__global__ void reorder_kernel(const int* __restrict__ e0, int* __restrict__ pos0,
                               int2* __restrict__ se0,
                               const int* __restrict__ e1, int* __restrict__ pos1,
                               int2* __restrict__ se1)
{
    const int* edges = blockIdx.y ? e1 : e0;
    int* pos = blockIdx.y ? pos1 : pos0;
    int2* se = blockIdx.y ? se1 : se0;
    int e = blockIdx.x * 256 + threadIdx.x;
    if (e >= EE) return;
    int p = atomicAdd(&pos[edges[EE + e]], 1);
    se[p] = make_int2(edges[e], e);
}

// ---------------- fused aggregation --------------------------------------
// One kernel per layer: acc = sum_sim + sum_rat (two edge loops, 4-way
// unrolled to break the se->gather dependent-latency chain), then
// hb = bf16(relu?(y_self + bias + acc)), padded to HPAD.

__device__ __forceinline__ void edge_accum(
    const unsigned short* __restrict__ msg,
    const int* __restrict__ off, const int2* __restrict__ se,
    int n, int w, int j4, bool act, float4& acc)
{
    const int e1 = off[n + 1];
    int i = off[n] + w;
    // 4 independent se loads, then 4 independent gathers: latency amortized 4x
    for (; i + 12 < e1; i += 16) {
        const int s0 = se[i].x;
        const int s1 = se[i + 4].x;
        const int s2 = se[i + 8].x;
        const int s3 = se[i + 12].x;
        if (act) {
            ushort4 v0 = *(const ushort4*)(msg + (size_t)s0 * 200 + j4);
            ushort4 v1 = *(const ushort4*)(msg + (size_t)s1 * 200 + j4);
            ushort4 v2 = *(const ushort4*)(msg + (size_t)s2 * 200 + j4);
            ushort4 v3 = *(const ushort4*)(msg + (size_t)s3 * 200 + j4);
            acc.x += (b2f(v0.x) + b2f(v1.x)) + (b2f(v2.x) + b2f(v3.x));
            acc.y += (b2f(v0.y) + b2f(v1.y)) + (b2f(v2.y) + b2f(v3.y));
            acc.z += (b2f(v0.z) + b2f(v1.z)) + (b2f(v2.z) + b2f(v3.z));
            acc.w += (b2f(v0.w) + b2f(v1.w)) + (b2f(v2.w) + b2f(v3.w));
        }
    }
    for (; i < e1; i += 4) {
        const int s = se[i].x;
        if (act) {
            ushort4 v = *(const ushort4*)(msg + (size_t)s * 200 + j4);
            acc.x += b2f(v.x); acc.y += b2f(v.y);
            acc.z += b2f(v.z); acc.w += b2f(v.w);
        }
    }
}

__global__ __launch_bounds__(256) void agg_fused_kernel(
    const unsigned short* __restrict__ msg_sim,
    const unsigned short* __restrict__ msg_rat,
    const int* __restrict__ off_sim, const int2* __restrict__ se_sim,
    const int* __restrict__ off_rat, const int2* __restrict__ se_rat,
    const float* __restrict__ y_self, const float* __restrict__ bias,
    unsigned short* __restrict__ hb, int relu)
{
    __shared__ float part[4][200];
    const int n = blockIdx.x;
    const int w = threadIdx.x >> 6;
    const int lane = threadIdx.x & 63;
    const int j4 = lane << 2;
    const bool act = lane < 50;

    float4 acc = {0.f, 0.f, 0.f, 0.f};
    edge_accum(msg_sim, off_sim, se_sim, n, w, j4, act, acc);
    edge_accum(msg_rat, off_rat, se_rat, n, w, j4, act, acc);

    if (act) *(float4*)&part[w][j4] = acc;
    __syncthreads();
    const int j = threadIdx.x;
    if (j < 200) {
        float v = part[0][j] + part[1][j] + part[2][j] + part[3][j]
                + y_self[(size_t)n * 200 + j] + bias[j];
        if (relu) v = fmaxf(v, 0.f);
        hb[((size_t)n << 8) + j] = f2b(v);
    } else if (j < HPAD) {
        hb[((size_t)n << 8) + j] = 0;     // zero the pad (ws is poisoned)
    }
}

// ---------------- decoder: dst-grouped, hQ gathered from L2-resident array ---
__global__ __launch_bounds__(256) void pred_kernel(
    const unsigned short* __restrict__ hQb,  // [8192, HPAD] bf16
    const unsigned short* __restrict__ h2b,  // [8192, HPAD] bf16
    const int* __restrict__ off, const int2* __restrict__ se,
    const int* __restrict__ mask, float* __restrict__ out)
{
    const int n = blockIdx.x;
    const int w = threadIdx.x >> 6;
    const int lane = threadIdx.x & 63;
    float4 b = {0.f, 0.f, 0.f, 0.f};
    if (lane < 50) {
        ushort4 v = *(const ushort4*)(h2b + ((size_t)n << 8) + (lane << 2));
        b.x = b2f(v.x); b.y = b2f(v.y); b.z = b2f(v.z); b.w = b2f(v.w);
    }
    const int e1 = off[n + 1];
    int i = off[n] + w;
    for (; i + 12 < e1; i += 16) {
        const int2 p0 = se[i];
        const int2 p1 = se[i + 4];
        const int2 p2 = se[i + 8];
        const int2 p3 = se[i + 12];
        float s0 = 0.f, s1 = 0.f, s2 = 0.f, s3 = 0.f;
        if (lane < 50) {
            ushort4 a0 = *(const ushort4*)(hQb + ((size_t)p0.x << 8) + (lane << 2));
            ushort4 a1 = *(const ushort4*)(hQb + ((size_t)p1.x << 8) + (lane << 2));
            ushort4 a2 = *(const ushort4*)(hQb + ((size_t)p2.x << 8) + (lane << 2));
            ushort4 a3 = *(const ushort4*)(hQb + ((size_t)p3.x << 8) + (lane << 2));
            s0 = fmaf(b2f(a0.x), b.x, fmaf(b2f(a0.y), b.y,
                 fmaf(b2f(a0.z), b.z, b2f(a0.w) * b.w)));
            s1 = fmaf(b2f(a1.x), b.x, fmaf(b2f(a1.y), b.y,
                 fmaf(b2f(a1.z), b.z, b2f(a1.w) * b.w)));
            s2 = fmaf(b2f(a2.x), b.x, fmaf(b2f(a2.y), b.y,
                 fmaf(b2f(a2.z), b.z, b2f(a2.w) * b.w)));
            s3 = fmaf(b2f(a3.x), b.x, fmaf(b2f(a3.y), b.y,
                 fmaf(b2f(a3.z), b.z, b2f(a3.w) * b.w)));
        }
#pragma unroll
        for (int o = 32; o > 0; o >>= 1) {    // 4 independent reduce chains
            s0 += __shfl_down(s0, o, 64);
            s1 += __shfl_down(s1, o, 64);
            s2 += __shfl_down(s2, o, 64);
            s3 += __shfl_down(s3, o, 64);
        }
        if (lane == 0) {
            out[p0.y] = mask[p0.y] ? (s0 + 3.5f) : 0.f;
            out[p1.y] = mask[p1.y] ? (s1 + 3.5f) : 0.f;
            out[p2.y] = mask[p2.y] ? (s2 + 3.5f) : 0.f;
            out[p3.y] = mask[p3.y] ? (s3 + 3.5f) : 0.f;
        }
    }
    for (; i < e1; i += 4) {
        const int2 p = se[i];
        float s = 0.f;
        if (lane < 50) {
            ushort4 a = *(const ushort4*)(hQb + ((size_t)p.x << 8) + (lane << 2));
            s = fmaf(b2f(a.x), b.x, fmaf(b2f(a.y), b.y,
                fmaf(b2f(a.z), b.z, b2f(a.w) * b.w)));
        }
#pragma unroll
        for (int o = 32; o > 0; o >>= 1) s += __shfl_down(s, o, 64);
        if (lane == 0) out[p.y] = mask[p.y] ? (s + 3.5f) : 0.f;
    }
}

// ---------------- launch ----------------
extern "C" void kernel_launch(void* const* d_in, const int* in_sizes, int n_in,
                              void* d_out, int out_size, void* d_ws, size_t ws_size,
                              hipStream_t stream)
{
    const float* x       = (const float*)d_in[0];
    const int*   e_sim   = (const int*)d_in[1];
    const int*   e_rat   = (const int*)d_in[2];
    const int*   mask    = (const int*)d_in[3];
    const float* w1_self = (const float*)d_in[4];
    const float* w1_sim  = (const float*)d_in[5];
    const float* w1_rat  = (const float*)d_in[6];
    const float* b1      = (const float*)d_in[7];
    const float* w2_self = (const float*)d_in[8];
    const float* w2_sim  = (const float*)d_in[9];
    const float* w2_rat  = (const float*)d_in[10];
    const float* b2      = (const float*)d_in[11];
    const float* Q       = (const float*)d_in[12];
    float* out = (float*)d_out;

    char* p = (char*)d_ws;
    auto alloc = [&](size_t bytes) -> char* {
        char* r = p;
        p += (bytes + 255) & ~(size_t)255;
        return r;
    };
    unsigned short* xb    = (unsigned short*)alloc((size_t)NN * NN * 2);   // 134 MB
    unsigned short* wbT1  = (unsigned short*)alloc((size_t)NP * NN * 2);   // 10.5 MB
    unsigned short* wbT2  = (unsigned short*)alloc((size_t)NP * HPAD * 2);
    unsigned short* QT    = (unsigned short*)alloc((size_t)HPAD * HPAD * 2);
    float* ypart = (float*)alloc((size_t)4 * NN * NP * 4);                 // 84 MB
    float* y_self = (float*)alloc((size_t)NN * 200 * 4);                   // 6.6 MB
    unsigned short* y_simb = (unsigned short*)alloc((size_t)NN * 200 * 2); // 3.28 MB
    unsigned short* y_ratb = (unsigned short*)alloc((size_t)NN * 200 * 2); // 3.28 MB
    unsigned short* h1b = (unsigned short*)alloc((size_t)NN * HPAD * 2);
    unsigned short* h2b = (unsigned short*)alloc((size_t)NN * HPAD * 2);
    unsigned short* hQb = (unsigned short*)alloc((size_t)NN * HPAD * 2);
    int* deg_sim = (int*)alloc(NN * 4);
    int* deg_rat = (int*)alloc(NN * 4);
    int* off_sim = (int*)alloc((NN + 1) * 4);
    int* off_rat = (int*)alloc((NN + 1) * 4);
    int* pos_sim = (int*)alloc(NN * 4);
    int* pos_rat = (int*)alloc(NN * 4);
    int2* se_sim = (int2*)alloc((size_t)EE * 8);
    int2* se_rat = (int2*)alloc((size_t)EE * 8);

    const dim3 blk(256);
    const dim3 tblk(32, 8);

    // conversions
    cvt_f2b_kernel<<<(NN * NN / 4) / 256, blk, 0, stream>>>(x, xb, NN * NN / 4);
    transpose_w_kernel<<<dim3(NN / 32, NP / 32), tblk, 0, stream>>>(
        w1_self, w1_sim, w1_rat, wbT1, NN, NN, 600);
    transpose_w_kernel<<<dim3(HPAD / 32, NP / 32), tblk, 0, stream>>>(
        w2_self, w2_sim, w2_rat, wbT2, HPAD, 200, 600);
    transpose_w_kernel<<<dim3(HPAD / 32, HPAD / 32), tblk, 0, stream>>>(
        Q, Q, Q, QT, HPAD, 200, 200);

    // edge sorts (dst-grouped, payload (src,eid)), both types batched
    hipMemsetAsync(deg_sim, 0, 2 * NN * 4, stream);   // deg_sim+deg_rat contiguous
    hist_kernel<<<dim3(EE / 256, 2), blk, 0, stream>>>(e_sim, e_rat, deg_sim, deg_rat);
    scan_kernel<<<2, blk, 0, stream>>>(deg_sim, off_sim, pos_sim,
                                       deg_rat, off_rat, pos_rat);
    reorder_kernel<<<dim3(EE / 256, 2), blk, 0, stream>>>(
        e_sim, pos_sim, se_sim, e_rat, pos_rat, se_rat);

    // layer 1 (split-K = 4: 1280 blocks = exactly 5 per CU, no tail imbalance)
    gemm_mfma<<<dim3(NP / 128, NN / 128, 4), blk, 0, stream>>>(
        xb, wbT1, ypart, nullptr, NN, NN / 4, NP, (size_t)NN * NP,
        nullptr, nullptr, nullptr);
    combine_kernel<<<NN * 50 / 256, blk, 0, stream>>>(
        ypart, 4, y_self, y_simb, y_ratb);
    agg_fused_kernel<<<NN, blk, 0, stream>>>(
        y_simb, y_ratb, off_sim, se_sim, off_rat, se_rat, y_self, b1, h1b, 1);

    // layer 2 (combine fused into GEMM epilogue: no ypart roundtrip)
    gemm_mfma<<<dim3(NP / 128, NN / 128, 1), blk, 0, stream>>>(
        h1b, wbT2, nullptr, nullptr, HPAD, HPAD, NP, 0,
        y_self, y_simb, y_ratb);
    agg_fused_kernel<<<NN, blk, 0, stream>>>(
        y_simb, y_ratb, off_sim, se_sim, off_rat, se_rat, y_self, b2, h2b, 0);

    // decoder (GEMM emits bf16 directly into hQb)
    gemm_mfma<<<dim3(HPAD / 128, NN / 128, 1), blk, 0, stream>>>(
        h2b, QT, nullptr, hQb, HPAD, HPAD, HPAD, 0,
        nullptr, nullptr, nullptr);
    pred_kernel<<<NN, blk, 0, stream>>>(hQb, h2b, off_rat, se_rat, mask, out);
}

// Round 3
// 833.605 us; speedup vs baseline: 1.1709x; 1.0033x over previous
//
#include <hip/hip_runtime.h>

#define NN 8192
#define EE 524288
#define HPAD 256   // hidden 200 padded to 256
#define NP 640     // 3*200 output cols padded to 640 (5 x 128 tiles)
#define PSS ((size_t)NN * 200)   // self-partial plane stride (fp32)
#define PSM ((size_t)NN * 400)   // msg-partial plane stride (bf16)

using s16x8 = __attribute__((ext_vector_type(8))) short;
using u16x8 = __attribute__((ext_vector_type(8))) unsigned short;
using f32x4 = __attribute__((ext_vector_type(4))) float;

__device__ __forceinline__ unsigned short f2b(float f) {
    unsigned u = __float_as_uint(f);
    u = (u + 0x7FFFu + ((u >> 16) & 1u)) >> 16;   // round-to-nearest-even
    return (unsigned short)u;
}
__device__ __forceinline__ float b2f(unsigned short u) {
    return __uint_as_float((unsigned)u << 16);
}

// async 16B global->LDS (direct DMA). Dest is wave-uniform base + lane*16.
__device__ __forceinline__ void async16(const unsigned short* g, unsigned short* l)
{
    __builtin_amdgcn_global_load_lds(
        (const __attribute__((address_space(1))) unsigned int*)g,
        (__attribute__((address_space(3))) unsigned int*)l, 16, 0, 0);
}

// ---------------- conversions ----------------

// 8 floats/thread, one 16B store (hipcc won't merge 2x ushort4 stores itself)
__global__ void cvt_f2b_kernel(const float* __restrict__ in,
                               unsigned short* __restrict__ out, int n8)
{
    int i = blockIdx.x * 256 + threadIdx.x;
    if (i >= n8) return;
    float4 v0 = ((const float4*)in)[2 * i];
    float4 v1 = ((const float4*)in)[2 * i + 1];
    u16x8 o;
    o[0] = f2b(v0.x); o[1] = f2b(v0.y); o[2] = f2b(v0.z); o[3] = f2b(v0.w);
    o[4] = f2b(v1.x); o[5] = f2b(v1.y); o[6] = f2b(v1.z); o[7] = f2b(v1.w);
    ((u16x8*)out)[i] = o;
}

// out[n][k] (bf16, [Nout, Kout]) = concat(w0|w1|w2)[k][n], zero-padded.
// Batched over blockIdx.z: z=0 -> {w1_*, wbT1, Kout=NN, Kreal=NN}
//                          z=1 -> {w2_*, wbT2, Kout=HPAD, Kreal=200}
//                          z=2 -> {Q,Q,Q,  QT, Kout=HPAD, Kreal=200, Nreal=200}
__global__ void transpose_w_kernel(
    const float* __restrict__ u0, const float* __restrict__ u1,
    const float* __restrict__ u2,
    const float* __restrict__ v0, const float* __restrict__ v1,
    const float* __restrict__ v2,
    const float* __restrict__ Q,
    unsigned short* __restrict__ o0, unsigned short* __restrict__ o1,
    unsigned short* __restrict__ o2)
{
    const int zc = blockIdx.z;
    const float *w0, *w1, *w2;
    unsigned short* out;
    int Kout, Kreal, Nreal;
    if (zc == 0)      { w0 = u0; w1 = u1; w2 = u2; out = o0; Kout = NN;   Kreal = NN;  Nreal = 600; }
    else if (zc == 1) { w0 = v0; w1 = v1; w2 = v2; out = o1; Kout = HPAD; Kreal = 200; Nreal = 600; }
    else              { w0 = Q;  w1 = Q;  w2 = Q;  out = o2; Kout = HPAD; Kreal = 200; Nreal = 200; }
    const int kb = blockIdx.x << 5;
    const int nb = blockIdx.y << 5;
    if (kb >= Kout) return;               // over-provisioned batched grid
    __shared__ float tile[32][33];
    const int tx = threadIdx.x, ty = threadIdx.y;   // 32 x 8
    const int n = nb + tx;
    const float* w = (n < 200) ? w0 : (n < 400) ? w1 : w2;
    const int c = (n < 200) ? n : (n < 400) ? n - 200 : n - 400;
#pragma unroll
    for (int i = 0; i < 4; ++i) {
        const int k = kb + ty + (i << 3);
        float v = 0.f;
        if (n < Nreal && k < Kreal) v = w[(size_t)k * 200 + c];
        tile[ty + (i << 3)][tx] = v;
    }
    __syncthreads();
#pragma unroll
    for (int i = 0; i < 4; ++i) {
        const int nn = nb + ty + (i << 3);
        out[(size_t)nn * Kout + kb + tx] = f2b(tile[tx][ty + (i << 3)]);
    }
}

// ---------------- MFMA GEMM: dbuf LDS + async DMA, 1 barrier per K-step ------
// LDS layout: slot s of row r holds k-chunk s^(r&7)  (conflict-free ds_read).
// XCD-chunked swizzle (T1). Epilogue modes:
//   ymp!=null -> split-K planes: cols<200 fp32 -> ysp plane, 200..599 bf16 -> ymp
//   ysb!=null -> fused combine (y_self fp32 / y_simb / y_ratb)
//   else      -> bf16 C (ldc)
__global__ __launch_bounds__(256) void gemm_mfma(
    const unsigned short* __restrict__ A,
    const unsigned short* __restrict__ BT,
    int lda, int KC,
    unsigned short* __restrict__ Cb, int ldc,
    float* __restrict__ ys, unsigned short* __restrict__ ysb,
    unsigned short* __restrict__ yrb,
    float* __restrict__ ysp, unsigned short* __restrict__ ymp)
{
    __shared__ unsigned short As[2][128 * 64];
    __shared__ unsigned short Bs[2][128 * 64];
    const int tid  = threadIdx.x;
    const int lane = tid & 63;
    const int w    = tid >> 6;

    // XCD-aware remap (bijective; nwg % 8 == 0 for all our launches)
    const int nx   = gridDim.x;
    const int flat = blockIdx.y * nx + blockIdx.x;
    const int cpx  = (nx * gridDim.y) >> 3;
    const int orig = (flat & 7) * cpx + (flat >> 3);
    const int by   = orig / nx;
    const int bx   = orig - by * nx;

    const int row0 = by << 7;
    const int col0 = bx << 7;
    const int z    = blockIdx.z;
    const int wm = (w >> 1) << 6;
    const int wn = (w & 1) << 6;

    const int sr = lane >> 3;             // row within wave's 8-row strip
    const int sc = (lane & 7) ^ sr;       // global chunk to fetch (xor-permuted)
    const size_t kbase = (size_t)z * KC + ((size_t)sc << 3);
    const unsigned short* aG = A  + (size_t)(row0 + w * 8 + sr) * lda + kbase;
    const unsigned short* bG = BT + (size_t)(col0 + w * 8 + sr) * lda + kbase;
    const int ldsOff = w * 8;             // wave's strip base row

    const f32x4 zero = {0.f, 0.f, 0.f, 0.f};
    f32x4 acc[4][4];
#pragma unroll
    for (int i = 0; i < 4; ++i)
#pragma unroll
        for (int j = 0; j < 4; ++j) acc[i][j] = zero;

    // stage tile 0 into buf 0
#pragma unroll
    for (int it = 0; it < 4; ++it) {
        async16(aG + (size_t)(it * 32) * lda, &As[0][(it * 32 + ldsOff) << 6]);
        async16(bG + (size_t)(it * 32) * lda, &Bs[0][(it * 32 + ldsOff) << 6]);
    }
    __syncthreads();

    const int T = KC >> 6;
    for (int t = 0; t < T; ++t) {
        const int cur = t & 1;
        if (t + 1 < T) {
            const int ko = (t + 1) << 6;
#pragma unroll
            for (int it = 0; it < 4; ++it) {
                async16(aG + (size_t)(it * 32) * lda + ko,
                        &As[cur ^ 1][(it * 32 + ldsOff) << 6]);
                async16(bG + (size_t)(it * 32) * lda + ko,
                        &Bs[cur ^ 1][(it * 32 + ldsOff) << 6]);
            }
        }
#pragma unroll
        for (int kk = 0; kk < 2; ++kk) {
            const int q  = (kk << 2) + (lane >> 4);
            const int sl = (q ^ (lane & 7)) << 3;
            s16x8 af[4], bfv[4];
#pragma unroll
            for (int i = 0; i < 4; ++i) {
                const int rm = wm + (i << 4) + (lane & 15);
                af[i]  = *(const s16x8*)(&As[cur][(rm << 6) + sl]);
                const int rn = wn + (i << 4) + (lane & 15);
                bfv[i] = *(const s16x8*)(&Bs[cur][(rn << 6) + sl]);
            }
#pragma unroll
            for (int i = 0; i < 4; ++i)
#pragma unroll
                for (int j = 0; j < 4; ++j)
                    acc[i][j] = __builtin_amdgcn_mfma_f32_16x16x32_bf16(
                        af[i], bfv[j], acc[i][j], 0, 0, 0);
        }
        __syncthreads();   // drains this iter's DMA; protects buf swap
    }

    const int cr = (lane >> 4) << 2;      // C/D: row = quad*4 + r, col = lane&15
    const int cc = lane & 15;
    if (ymp) {
        // split-K planes: self fp32, messages bf16, pad dropped
        float* sp = ysp + (size_t)z * PSS;
        unsigned short* mp = ymp + (size_t)z * PSM;
#pragma unroll
        for (int i = 0; i < 4; ++i)
#pragma unroll
            for (int j = 0; j < 4; ++j)
#pragma unroll
                for (int r = 0; r < 4; ++r) {
                    const int n = row0 + wm + (i << 4) + cr + r;
                    const int c = col0 + wn + (j << 4) + cc;
                    const float v = acc[i][j][r];
                    if (c < 200)      sp[(size_t)n * 200 + c] = v;
                    else if (c < 600) mp[(size_t)n * 400 + (c - 200)] = f2b(v);
                }
    } else if (ysb) {
        // fused combine epilogue (layer-2 GEMM, no split-K)
#pragma unroll
        for (int i = 0; i < 4; ++i)
#pragma unroll
            for (int j = 0; j < 4; ++j)
#pragma unroll
                for (int r = 0; r < 4; ++r) {
                    const int n = row0 + wm + (i << 4) + cr + r;
                    const int c = col0 + wn + (j << 4) + cc;
                    const float v = acc[i][j][r];
                    if (c < 200)      ys [(size_t)n * 200 + c]        = v;
                    else if (c < 400) ysb[(size_t)n * 200 + (c - 200)] = f2b(v);
                    else if (c < 600) yrb[(size_t)n * 200 + (c - 400)] = f2b(v);
                }
    } else {
#pragma unroll
        for (int i = 0; i < 4; ++i)
#pragma unroll
            for (int j = 0; j < 4; ++j)
#pragma unroll
                for (int r = 0; r < 4; ++r)
                    Cb[(size_t)(row0 + wm + (i << 4) + cr + r) * ldc
                       + (col0 + wn + (j << 4) + cc)] = f2b(acc[i][j][r]);
    }
}

// ---------------- combine: sum 4 split planes -> self fp32 + 2x bf16 ---------
__global__ void combine_kernel(const float* __restrict__ ysp,
                               const unsigned short* __restrict__ ymp,
                               float* __restrict__ y_self,
                               unsigned short* __restrict__ y_simb,
                               unsigned short* __restrict__ y_ratb)
{
    int t = blockIdx.x * 256 + threadIdx.x;    // n*50 + j4chunk
    int n = t / 50, j4 = (t - n * 50) << 2;
    float4 s = {0.f, 0.f, 0.f, 0.f};
    float4 m = {0.f, 0.f, 0.f, 0.f};
    float4 r = {0.f, 0.f, 0.f, 0.f};
#pragma unroll
    for (int z = 0; z < 4; ++z) {
        float4 s2 = *(const float4*)(ysp + z * PSS + (size_t)n * 200 + j4);
        ushort4 m2 = *(const ushort4*)(ymp + z * PSM + (size_t)n * 400 + j4);
        ushort4 r2 = *(const ushort4*)(ymp + z * PSM + (size_t)n * 400 + 200 + j4);
        s.x += s2.x; s.y += s2.y; s.z += s2.z; s.w += s2.w;
        m.x += b2f(m2.x); m.y += b2f(m2.y); m.z += b2f(m2.z); m.w += b2f(m2.w);
        r.x += b2f(r2.x); r.y += b2f(r2.y); r.z += b2f(r2.z); r.w += b2f(r2.w);
    }
    *(float4*)(y_self + (size_t)n * 200 + j4) = s;
    ushort4 mo, ro;
    mo.x = f2b(m.x); mo.y = f2b(m.y); mo.z = f2b(m.z); mo.w = f2b(m.w);
    ro.x = f2b(r.x); ro.y = f2b(r.y); ro.z = f2b(r.z); ro.w = f2b(r.w);
    *(ushort4*)(y_simb + (size_t)n * 200 + j4) = mo;
    *(ushort4*)(y_ratb + (size_t)n * 200 + j4) = ro;
}

// ---------------- edge sort (counting sort by dst, payload = (src, eid)) -----

__global__ void hist_kernel(const int* __restrict__ e0, const int* __restrict__ e1,
                            int* __restrict__ d0, int* __restrict__ d1)
{
    const int* edges = blockIdx.y ? e1 : e0;
    int* deg = blockIdx.y ? d1 : d0;
    int e = blockIdx.x * 256 + threadIdx.x;
    if (e < EE) atomicAdd(&deg[edges[EE + e]], 1);
}

__global__ void scan_kernel(const int* __restrict__ deg0, int* __restrict__ off0,
                            int* __restrict__ pos0,
                            const int* __restrict__ deg1, int* __restrict__ off1,
                            int* __restrict__ pos1)
{
    const int* deg = blockIdx.x ? deg1 : deg0;
    int* off = blockIdx.x ? off1 : off0;
    int* pos = blockIdx.x ? pos1 : pos0;
    __shared__ int part[256];
    const int t = threadIdx.x;
    const int base = t * 32;
    int s = 0;
#pragma unroll
    for (int i = 0; i < 32; ++i) s += deg[base + i];
    part[t] = s;
    __syncthreads();
    for (int d = 1; d < 256; d <<= 1) {
        int v = (t >= d) ? part[t - d] : 0;
        __syncthreads();
        part[t] += v;
        __syncthreads();
    }
    int run = (t == 0) ? 0 : part[t - 1];
    for (int i = 0; i < 32; ++i) {
        off[base + i] = run;
        pos[base + i] = run;
        run += deg[base + i];
    }
    if (t == 255) off[NN] = run;
}

__global__ void reorder_kernel(const int* __restrict__ e0, int* __restrict__ pos0,
                               int2* __restrict__ se0,
                               const int* __restrict__ e1, int* __restrict__ pos1,
                               int2* __restrict__ se1)
{
    const int* edges = blockIdx.y ? e1 : e0;
    int* pos = blockIdx.y ? pos1 : pos0;
    int2* se = blockIdx.y ? se1 : se0;
    int e = blockIdx.x * 256 + threadIdx.x;
    if (e >= EE) return;
    int p = atomicAdd(&pos[edges[EE + e]], 1);
    se[p] = make_int2(edges[e], e);
}

// ---------------- fused aggregation --------------------------------------

__device__ __forceinline__ void edge_accum(
    const unsigned short* __restrict__ msg,
    const int* __restrict__ off, const int2* __restrict__ se,
    int n, int w, int j4, bool act, float4& acc)
{
    const int e1 = off[n + 1];
    int i = off[n] + w;
    // 4 independent se loads, then 4 independent gathers: latency amortized 4x
    for (; i + 12 < e1; i += 16) {
        const int s0 = se[i].x;
        const int s1 = se[i + 4].x;
        const int s2 = se[i + 8].x;
        const int s3 = se[i + 12].x;
        if (act) {
            ushort4 v0 = *(const ushort4*)(msg + (size_t)s0 * 200 + j4);
            ushort4 v1 = *(const ushort4*)(msg + (size_t)s1 * 200 + j4);
            ushort4 v2 = *(const ushort4*)(msg + (size_t)s2 * 200 + j4);
            ushort4 v3 = *(const ushort4*)(msg + (size_t)s3 * 200 + j4);
            acc.x += (b2f(v0.x) + b2f(v1.x)) + (b2f(v2.x) + b2f(v3.x));
            acc.y += (b2f(v0.y) + b2f(v1.y)) + (b2f(v2.y) + b2f(v3.y));
            acc.z += (b2f(v0.z) + b2f(v1.z)) + (b2f(v2.z) + b2f(v3.z));
            acc.w += (b2f(v0.w) + b2f(v1.w)) + (b2f(v2.w) + b2f(v3.w));
        }
    }
    for (; i < e1; i += 4) {
        const int s = se[i].x;
        if (act) {
            ushort4 v = *(const ushort4*)(msg + (size_t)s * 200 + j4);
            acc.x += b2f(v.x); acc.y += b2f(v.y);
            acc.z += b2f(v.z); acc.w += b2f(v.w);
        }
    }
}

__global__ __launch_bounds__(256) void agg_fused_kernel(
    const unsigned short* __restrict__ msg_sim,
    const unsigned short* __restrict__ msg_rat,
    const int* __restrict__ off_sim, const int2* __restrict__ se_sim,
    const int* __restrict__ off_rat, const int2* __restrict__ se_rat,
    const float* __restrict__ y_self, const float* __restrict__ bias,
    unsigned short* __restrict__ hb, int relu)
{
    __shared__ float part[4][200];
    const int n = blockIdx.x;
    const int w = threadIdx.x >> 6;
    const int lane = threadIdx.x & 63;
    const int j4 = lane << 2;
    const bool act = lane < 50;

    float4 acc = {0.f, 0.f, 0.f, 0.f};
    edge_accum(msg_sim, off_sim, se_sim, n, w, j4, act, acc);
    edge_accum(msg_rat, off_rat, se_rat, n, w, j4, act, acc);

    if (act) *(float4*)&part[w][j4] = acc;
    __syncthreads();
    const int j = threadIdx.x;
    if (j < 200) {
        float v = part[0][j] + part[1][j] + part[2][j] + part[3][j]
                + y_self[(size_t)n * 200 + j] + bias[j];
        if (relu) v = fmaxf(v, 0.f);
        hb[((size_t)n << 8) + j] = f2b(v);
    } else if (j < HPAD) {
        hb[((size_t)n << 8) + j] = 0;     // zero the pad (ws is poisoned)
    }
}

// ---------------- decoder: dst-grouped, hQ gathered from L2-resident array ---
__global__ __launch_bounds__(256) void pred_kernel(
    const unsigned short* __restrict__ hQb,  // [8192, HPAD] bf16
    const unsigned short* __restrict__ h2b,  // [8192, HPAD] bf16
    const int* __restrict__ off, const int2* __restrict__ se,
    const int* __restrict__ mask, float* __restrict__ out)
{
    const int n = blockIdx.x;
    const int w = threadIdx.x >> 6;
    const int lane = threadIdx.x & 63;
    float4 b = {0.f, 0.f, 0.f, 0.f};
    if (lane < 50) {
        ushort4 v = *(const ushort4*)(h2b + ((size_t)n << 8) + (lane << 2));
        b.x = b2f(v.x); b.y = b2f(v.y); b.z = b2f(v.z); b.w = b2f(v.w);
    }
    const int e1 = off[n + 1];
    int i = off[n] + w;
    for (; i + 12 < e1; i += 16) {
        const int2 p0 = se[i];
        const int2 p1 = se[i + 4];
        const int2 p2 = se[i + 8];
        const int2 p3 = se[i + 12];
        float s0 = 0.f, s1 = 0.f, s2 = 0.f, s3 = 0.f;
        if (lane < 50) {
            ushort4 a0 = *(const ushort4*)(hQb + ((size_t)p0.x << 8) + (lane << 2));
            ushort4 a1 = *(const ushort4*)(hQb + ((size_t)p1.x << 8) + (lane << 2));
            ushort4 a2 = *(const ushort4*)(hQb + ((size_t)p2.x << 8) + (lane << 2));
            ushort4 a3 = *(const ushort4*)(hQb + ((size_t)p3.x << 8) + (lane << 2));
            s0 = fmaf(b2f(a0.x), b.x, fmaf(b2f(a0.y), b.y,
                 fmaf(b2f(a0.z), b.z, b2f(a0.w) * b.w)));
            s1 = fmaf(b2f(a1.x), b.x, fmaf(b2f(a1.y), b.y,
                 fmaf(b2f(a1.z), b.z, b2f(a1.w) * b.w)));
            s2 = fmaf(b2f(a2.x), b.x, fmaf(b2f(a2.y), b.y,
                 fmaf(b2f(a2.z), b.z, b2f(a2.w) * b.w)));
            s3 = fmaf(b2f(a3.x), b.x, fmaf(b2f(a3.y), b.y,
                 fmaf(b2f(a3.z), b.z, b2f(a3.w) * b.w)));
        }
#pragma unroll
        for (int o = 32; o > 0; o >>= 1) {    // 4 independent reduce chains
            s0 += __shfl_down(s0, o, 64);
            s1 += __shfl_down(s1, o, 64);
            s2 += __shfl_down(s2, o, 64);
            s3 += __shfl_down(s3, o, 64);
        }
        if (lane == 0) {
            out[p0.y] = mask[p0.y] ? (s0 + 3.5f) : 0.f;
            out[p1.y] = mask[p1.y] ? (s1 + 3.5f) : 0.f;
            out[p2.y] = mask[p2.y] ? (s2 + 3.5f) : 0.f;
            out[p3.y] = mask[p3.y] ? (s3 + 3.5f) : 0.f;
        }
    }
    for (; i < e1; i += 4) {
        const int2 p = se[i];
        float s = 0.f;
        if (lane < 50) {
            ushort4 a = *(const ushort4*)(hQb + ((size_t)p.x << 8) + (lane << 2));
            s = fmaf(b2f(a.x), b.x, fmaf(b2f(a.y), b.y,
                fmaf(b2f(a.z), b.z, b2f(a.w) * b.w)));
        }
#pragma unroll
        for (int o = 32; o > 0; o >>= 1) s += __shfl_down(s, o, 64);
        if (lane == 0) out[p.y] = mask[p.y] ? (s + 3.5f) : 0.f;
    }
}

// ---------------- launch ----------------
extern "C" void kernel_launch(void* const* d_in, const int* in_sizes, int n_in,
                              void* d_out, int out_size, void* d_ws, size_t ws_size,
                              hipStream_t stream)
{
    const float* x       = (const float*)d_in[0];
    const int*   e_sim   = (const int*)d_in[1];
    const int*   e_rat   = (const int*)d_in[2];
    const int*   mask    = (const int*)d_in[3];
    const float* w1_self = (const float*)d_in[4];
    const float* w1_sim  = (const float*)d_in[5];
    const float* w1_rat  = (const float*)d_in[6];
    const float* b1      = (const float*)d_in[7];
    const float* w2_self = (const float*)d_in[8];
    const float* w2_sim  = (const float*)d_in[9];
    const float* w2_rat  = (const float*)d_in[10];
    const float* b2      = (const float*)d_in[11];
    const float* Q       = (const float*)d_in[12];
    float* out = (float*)d_out;

    char* p = (char*)d_ws;
    auto alloc = [&](size_t bytes) -> char* {
        char* r = p;
        p += (bytes + 255) & ~(size_t)255;
        return r;
    };
    unsigned short* xb    = (unsigned short*)alloc((size_t)NN * NN * 2);   // 134 MB
    unsigned short* wbT1  = (unsigned short*)alloc((size_t)NP * NN * 2);   // 10.5 MB
    unsigned short* wbT2  = (unsigned short*)alloc((size_t)NP * HPAD * 2);
    unsigned short* QT    = (unsigned short*)alloc((size_t)HPAD * HPAD * 2);
    float* ypart_s = (float*)alloc(4 * PSS * 4);                           // 26 MB
    unsigned short* ypart_m = (unsigned short*)alloc(4 * PSM * 2);         // 26 MB
    float* y_self = (float*)alloc((size_t)NN * 200 * 4);                   // 6.6 MB
    unsigned short* y_simb = (unsigned short*)alloc((size_t)NN * 200 * 2); // 3.28 MB
    unsigned short* y_ratb = (unsigned short*)alloc((size_t)NN * 200 * 2); // 3.28 MB
    unsigned short* h1b = (unsigned short*)alloc((size_t)NN * HPAD * 2);
    unsigned short* h2b = (unsigned short*)alloc((size_t)NN * HPAD * 2);
    unsigned short* hQb = (unsigned short*)alloc((size_t)NN * HPAD * 2);
    int* deg_sim = (int*)alloc(NN * 4);
    int* deg_rat = (int*)alloc(NN * 4);
    int* off_sim = (int*)alloc((NN + 1) * 4);
    int* off_rat = (int*)alloc((NN + 1) * 4);
    int* pos_sim = (int*)alloc(NN * 4);
    int* pos_rat = (int*)alloc(NN * 4);
    int2* se_sim = (int2*)alloc((size_t)EE * 8);
    int2* se_rat = (int2*)alloc((size_t)EE * 8);

    const dim3 blk(256);
    const dim3 tblk(32, 8);

    // conversions (all three weight transposes in ONE dispatch; z=0 needs the
    // full 256-wide k-grid, z=1/2 early-out above kb>=HPAD)
    cvt_f2b_kernel<<<(NN * NN / 8) / 256, blk, 0, stream>>>(x, xb, NN * NN / 8);
    transpose_w_kernel<<<dim3(NN / 32, NP / 32, 3), tblk, 0, stream>>>(
        w1_self, w1_sim, w1_rat, w2_self, w2_sim, w2_rat, Q, wbT1, wbT2, QT);

    // edge sorts (dst-grouped, payload (src,eid)), both types batched
    hipMemsetAsync(deg_sim, 0, 2 * NN * 4, stream);   // deg_sim+deg_rat contiguous
    hist_kernel<<<dim3(EE / 256, 2), blk, 0, stream>>>(e_sim, e_rat, deg_sim, deg_rat);
    scan_kernel<<<2, blk, 0, stream>>>(deg_sim, off_sim, pos_sim,
                                       deg_rat, off_rat, pos_rat);
    reorder_kernel<<<dim3(EE / 256, 2), blk, 0, stream>>>(
        e_sim, pos_sim, se_sim, e_rat, pos_rat, se_rat);

    // layer 1 (split-K = 4; split fp32-self / bf16-msg partial planes)
    gemm_mfma<<<dim3(NP / 128, NN / 128, 4), blk, 0, stream>>>(
        xb, wbT1, NN, NN / 4, nullptr, 0,
        nullptr, nullptr, nullptr, ypart_s, ypart_m);
    combine_kernel<<<NN * 50 / 256, blk, 0, stream>>>(
        ypart_s, ypart_m, y_self, y_simb, y_ratb);
    agg_fused_kernel<<<NN, blk, 0, stream>>>(
        y_simb, y_ratb, off_sim, se_sim, off_rat, se_rat, y_self, b1, h1b, 1);

    // layer 2 (combine fused into GEMM epilogue: no ypart roundtrip)
    gemm_mfma<<<dim3(NP / 128, NN / 128, 1), blk, 0, stream>>>(
        h1b, wbT2, HPAD, HPAD, nullptr, 0,
        y_self, y_simb, y_ratb, nullptr, nullptr);
    agg_fused_kernel<<<NN, blk, 0, stream>>>(
        y_simb, y_ratb, off_sim, se_sim, off_rat, se_rat, y_self, b2, h2b, 0);

    // decoder (GEMM emits bf16 directly into hQb)
    gemm_mfma<<<dim3(HPAD / 128, NN / 128, 1), blk, 0, stream>>>(
        h2b, QT, HPAD, HPAD, hQb, HPAD,
        nullptr, nullptr, nullptr, nullptr, nullptr);
    pred_kernel<<<NN, blk, 0, stream>>>(hQb, h2b, off_rat, se_rat, mask, out);
}

// Round 5
// 803.007 us; speedup vs baseline: 1.2155x; 1.0381x over previous
//
#include <hip/hip_runtime.h>

#define NN 8192
#define EE 524288
#define HPAD 256   // hidden 200 padded to 256
#define NP 640     // 3*200 output cols padded to 640 (5 x 128 tiles)
#define PSS ((size_t)NN * 200)   // self-partial plane stride (fp32)
#define PSM ((size_t)NN * 400)   // msg-partial plane stride (bf16)

using s16x8 = __attribute__((ext_vector_type(8))) short;
using u16x8 = __attribute__((ext_vector_type(8))) unsigned short;
using f32x4 = __attribute__((ext_vector_type(4))) float;

__device__ __forceinline__ unsigned short f2b(float f) {
    unsigned u = __float_as_uint(f);
    u = (u + 0x7FFFu + ((u >> 16) & 1u)) >> 16;   // round-to-nearest-even
    return (unsigned short)u;
}
__device__ __forceinline__ float b2f(unsigned short u) {
    return __uint_as_float((unsigned)u << 16);
}
// packed f32x2 -> bf16x2, RNE (identical rounding to f2b); no builtin on gfx950
__device__ __forceinline__ unsigned pkbf16(float a, float b) {
    unsigned r;
    asm("v_cvt_pk_bf16_f32 %0, %1, %2" : "=v"(r) : "v"(a), "v"(b));
    return r;
}

// async 16B global->LDS (direct DMA). Dest is wave-uniform base + lane*16.
__device__ __forceinline__ void async16(const unsigned short* g, unsigned short* l)
{
    __builtin_amdgcn_global_load_lds(
        (const __attribute__((address_space(1))) unsigned int*)g,
        (__attribute__((address_space(3))) unsigned int*)l, 16, 0, 0);
}

// ---------------- weight transpose ----------------
// out[n][k] (bf16, [Nout, Kout]) = concat(w0|w1|w2)[k][n], zero-padded.
// Batched over blockIdx.z: z=0 -> {w1_*, wbT1, Kout=NN, Kreal=NN}
//                          z=1 -> {w2_*, wbT2, Kout=HPAD, Kreal=200}
//                          z=2 -> {Q,Q,Q,  QT, Kout=HPAD, Kreal=200, Nreal=200}
__global__ void transpose_w_kernel(
    const float* __restrict__ u0, const float* __restrict__ u1,
    const float* __restrict__ u2,
    const float* __restrict__ v0, const float* __restrict__ v1,
    const float* __restrict__ v2,
    const float* __restrict__ Q,
    unsigned short* __restrict__ o0, unsigned short* __restrict__ o1,
    unsigned short* __restrict__ o2)
{
    const int zc = blockIdx.z;
    const float *w0, *w1, *w2;
    unsigned short* out;
    int Kout, Kreal, Nreal;
    if (zc == 0)      { w0 = u0; w1 = u1; w2 = u2; out = o0; Kout = NN;   Kreal = NN;  Nreal = 600; }
    else if (zc == 1) { w0 = v0; w1 = v1; w2 = v2; out = o1; Kout = HPAD; Kreal = 200; Nreal = 600; }
    else              { w0 = Q;  w1 = Q;  w2 = Q;  out = o2; Kout = HPAD; Kreal = 200; Nreal = 200; }
    const int kb = blockIdx.x << 5;
    const int nb = blockIdx.y << 5;
    if (kb >= Kout) return;               // over-provisioned batched grid
    __shared__ float tile[32][33];
    const int tx = threadIdx.x, ty = threadIdx.y;   // 32 x 8
    const int n = nb + tx;
    const float* w = (n < 200) ? w0 : (n < 400) ? w1 : w2;
    const int c = (n < 200) ? n : (n < 400) ? n - 200 : n - 400;
#pragma unroll
    for (int i = 0; i < 4; ++i) {
        const int k = kb + ty + (i << 3);
        float v = 0.f;
        if (n < Nreal && k < Kreal) v = w[(size_t)k * 200 + c];
        tile[ty + (i << 3)][tx] = v;
    }
    __syncthreads();
#pragma unroll
    for (int i = 0; i < 4; ++i) {
        const int nn = nb + ty + (i << 3);
        out[(size_t)nn * Kout + kb + tx] = f2b(tile[tx][ty + (i << 3)]);
    }
}

// ---------------- MFMA GEMM: dbuf LDS, 1 barrier per K-step ------------------
// LDS layout: slot s of row r holds k-chunk s^(r&7)  (conflict-free ds_read).
// XCD-chunked swizzle (T1). A-staging:
//   AF32=0: async16 DMA from bf16 A (pre-swizzled global source).
//   AF32=1: A is fp32 (the raw x input). T14 async-split: issue 8 coalesced
//           dwordx4 loads for tile t+1 BEFORE the MFMA phase, convert with
//           v_cvt_pk_bf16_f32 + ds_write_b128 (swizzled) after it. Removes the
//           separate cvt kernel (402 MB of HBM traffic + one serial stage).
// Epilogue modes:
//   ymp!=null -> split-K planes: cols<200 fp32 -> ysp plane, 200..599 bf16 -> ymp
//   ysb!=null -> fused combine (y_self fp32 / y_simb / y_ratb)
//   else      -> bf16 C (ldc)
template<int AF32>
__global__ __launch_bounds__(256) void gemm_mfma(
    const void* __restrict__ Araw,
    const unsigned short* __restrict__ BT,
    int lda, int KC,
    unsigned short* __restrict__ Cb, int ldc,
    float* __restrict__ ys, unsigned short* __restrict__ ysb,
    unsigned short* __restrict__ yrb,
    float* __restrict__ ysp, unsigned short* __restrict__ ymp)
{
    __shared__ unsigned short As[2][128 * 64];
    __shared__ unsigned short Bs[2][128 * 64];
    const int tid  = threadIdx.x;
    const int lane = tid & 63;
    const int w    = tid >> 6;

    // XCD-aware remap (bijective; nwg % 8 == 0 for all our launches)
    const int nx   = gridDim.x;
    const int flat = blockIdx.y * nx + blockIdx.x;
    const int cpx  = (nx * gridDim.y) >> 3;
    const int orig = (flat & 7) * cpx + (flat >> 3);
    const int by   = orig / nx;
    const int bx   = orig - by * nx;

    const int row0 = by << 7;
    const int col0 = bx << 7;
    const int z    = blockIdx.z;
    const int wm = (w >> 1) << 6;
    const int wn = (w & 1) << 6;

    const int sr = lane >> 3;             // row within wave's 8-row strip
    const int sc = (lane & 7) ^ sr;       // global chunk to fetch (xor-permuted)
    const size_t kbase = (size_t)z * KC + ((size_t)sc << 3);
    const unsigned short* bG = BT + (size_t)(col0 + w * 8 + sr) * lda + kbase;
    const int ldsOff = w * 8;             // wave's strip base row

    // A staging setup
    const unsigned short* aG = nullptr;   // AF32=0 path
    const float* aF = nullptr;            // AF32=1 path
    int ar = 0, aq = 0;
    if constexpr (AF32) {
        ar = (w << 5) + (lane >> 2);      // base row (second pass adds 16)
        aq = lane & 3;                    // col quarter: cols [aq*16, aq*16+16)
        aF = (const float*)Araw
           + (size_t)(row0 + ar) * lda + (size_t)z * KC + aq * 16;
    } else {
        aG = (const unsigned short*)Araw
           + (size_t)(row0 + w * 8 + sr) * lda + kbase;
    }

    const f32x4 zero = {0.f, 0.f, 0.f, 0.f};
    f32x4 acc[4][4];
#pragma unroll
    for (int i = 0; i < 4; ++i)
#pragma unroll
        for (int j = 0; j < 4; ++j) acc[i][j] = zero;

    // ---- stage tile 0 into buf 0 ----
    if constexpr (AF32) {
        float4 lv[8];
#pragma unroll
        for (int p_ = 0; p_ < 2; ++p_) {
            const float4* s4 = (const float4*)(aF + (size_t)(p_ * 16) * lda);
#pragma unroll
            for (int u = 0; u < 4; ++u) lv[p_ * 4 + u] = s4[u];
        }
#pragma unroll
        for (int it = 0; it < 4; ++it)
            async16(bG + (size_t)(it * 32) * lda, &Bs[0][(it * 32 + ldsOff) << 6]);
#pragma unroll
        for (int p_ = 0; p_ < 2; ++p_) {
            const int r = ar + p_ * 16;
            unsigned short* dst = &As[0][r << 6];
#pragma unroll
            for (int d = 0; d < 2; ++d) {
                const int cch = aq * 2 + d;
                const int sl  = cch ^ (r & 7);
                const float4 x0 = lv[p_ * 4 + d * 2];
                const float4 x1 = lv[p_ * 4 + d * 2 + 1];
                uint4 o;
                o.x = pkbf16(x0.x, x0.y); o.y = pkbf16(x0.z, x0.w);
                o.z = pkbf16(x1.x, x1.y); o.w = pkbf16(x1.z, x1.w);
                *(uint4*)(dst + (sl << 3)) = o;
            }
        }
    } else {
#pragma unroll
        for (int it = 0; it < 4; ++it) {
            async16(aG + (size_t)(it * 32) * lda, &As[0][(it * 32 + ldsOff) << 6]);
            async16(bG + (size_t)(it * 32) * lda, &Bs[0][(it * 32 + ldsOff) << 6]);
        }
    }
    __syncthreads();

    const int T = KC >> 6;
    for (int t = 0; t < T; ++t) {
        const int cur = t & 1;
        float4 lv[8];
        if (t + 1 < T) {
            const int ko = (t + 1) << 6;
            if constexpr (AF32) {
                // early-issue A loads (latency hides under MFMA phase)
#pragma unroll
                for (int p_ = 0; p_ < 2; ++p_) {
                    const float4* s4 = (const float4*)(aF + (size_t)(p_ * 16) * lda + ko);
#pragma unroll
                    for (int u = 0; u < 4; ++u) lv[p_ * 4 + u] = s4[u];
                }
            } else {
#pragma unroll
                for (int it = 0; it < 4; ++it)
                    async16(aG + (size_t)(it * 32) * lda + ko,
                            &As[cur ^ 1][(it * 32 + ldsOff) << 6]);
            }
#pragma unroll
            for (int it = 0; it < 4; ++it)
                async16(bG + (size_t)(it * 32) * lda + ko,
                        &Bs[cur ^ 1][(it * 32 + ldsOff) << 6]);
        }
#pragma unroll
        for (int kk = 0; kk < 2; ++kk) {
            const int q  = (kk << 2) + (lane >> 4);
            const int sl = (q ^ (lane & 7)) << 3;
            s16x8 af[4], bfv[4];
#pragma unroll
            for (int i = 0; i < 4; ++i) {
                const int rm = wm + (i << 4) + (lane & 15);
                af[i]  = *(const s16x8*)(&As[cur][(rm << 6) + sl]);
                const int rn = wn + (i << 4) + (lane & 15);
                bfv[i] = *(const s16x8*)(&Bs[cur][(rn << 6) + sl]);
            }
#pragma unroll
            for (int i = 0; i < 4; ++i)
#pragma unroll
                for (int j = 0; j < 4; ++j)
                    acc[i][j] = __builtin_amdgcn_mfma_f32_16x16x32_bf16(
                        af[i], bfv[j], acc[i][j], 0, 0, 0);
        }
        if (t + 1 < T) {
            if constexpr (AF32) {
                // convert + swizzled LDS write (A-loads drained by compiler wait)
#pragma unroll
                for (int p_ = 0; p_ < 2; ++p_) {
                    const int r = ar + p_ * 16;
                    unsigned short* dst = &As[cur ^ 1][r << 6];
#pragma unroll
                    for (int d = 0; d < 2; ++d) {
                        const int cch = aq * 2 + d;
                        const int sl  = cch ^ (r & 7);
                        const float4 x0 = lv[p_ * 4 + d * 2];
                        const float4 x1 = lv[p_ * 4 + d * 2 + 1];
                        uint4 o;
                        o.x = pkbf16(x0.x, x0.y); o.y = pkbf16(x0.z, x0.w);
                        o.z = pkbf16(x1.x, x1.y); o.w = pkbf16(x1.z, x1.w);
                        *(uint4*)(dst + (sl << 3)) = o;
                    }
                }
            }
        }
        __syncthreads();   // drains DMA + orders ds_writes; protects buf swap
    }

    const int cr = (lane >> 4) << 2;      // C/D: row = quad*4 + r, col = lane&15
    const int cc = lane & 15;
    if (ymp) {
        // split-K planes: self fp32, messages bf16, pad dropped
        float* sp = ysp + (size_t)z * PSS;
        unsigned short* mp = ymp + (size_t)z * PSM;
#pragma unroll
        for (int i = 0; i < 4; ++i)
#pragma unroll
            for (int j = 0; j < 4; ++j)
#pragma unroll
                for (int r = 0; r < 4; ++r) {
                    const int n = row0 + wm + (i << 4) + cr + r;
                    const int c = col0 + wn + (j << 4) + cc;
                    const float v = acc[i][j][r];
                    if (c < 200)      sp[(size_t)n * 200 + c] = v;
                    else if (c < 600) mp[(size_t)n * 400 + (c - 200)] = f2b(v);
                }
    } else if (ysb) {
        // fused combine epilogue (layer-2 GEMM, no split-K)
#pragma unroll
        for (int i = 0; i < 4; ++i)
#pragma unroll
            for (int j = 0; j < 4; ++j)
#pragma unroll
                for (int r = 0; r < 4; ++r) {
                    const int n = row0 + wm + (i << 4) + cr + r;
                    const int c = col0 + wn + (j << 4) + cc;
                    const float v = acc[i][j][r];
                    if (c < 200)      ys [(size_t)n * 200 + c]        = v;
                    else if (c < 400) ysb[(size_t)n * 200 + (c - 200)] = f2b(v);
                    else if (c < 600) yrb[(size_t)n * 200 + (c - 400)] = f2b(v);
                }
    } else {
#pragma unroll
        for (int i = 0; i < 4; ++i)
#pragma unroll
            for (int j = 0; j < 4; ++j)
#pragma unroll
                for (int r = 0; r < 4; ++r)
                    Cb[(size_t)(row0 + wm + (i << 4) + cr + r) * ldc
                       + (col0 + wn + (j << 4) + cc)] = f2b(acc[i][j][r]);
    }
}

// ---------------- combine: sum 4 split planes -> self fp32 + 2x bf16 ---------
__global__ void combine_kernel(const float* __restrict__ ysp,
                               const unsigned short* __restrict__ ymp,
                               float* __restrict__ y_self,
                               unsigned short* __restrict__ y_simb,
                               unsigned short* __restrict__ y_ratb)
{
    int t = blockIdx.x * 256 + threadIdx.x;    // n*50 + j4chunk
    int n = t / 50, j4 = (t - n * 50) << 2;
    float4 s = {0.f, 0.f, 0.f, 0.f};
    float4 m = {0.f, 0.f, 0.f, 0.f};
    float4 r = {0.f, 0.f, 0.f, 0.f};
#pragma unroll
    for (int z = 0; z < 4; ++z) {
        float4 s2 = *(const float4*)(ysp + z * PSS + (size_t)n * 200 + j4);
        ushort4 m2 = *(const ushort4*)(ymp + z * PSM + (size_t)n * 400 + j4);
        ushort4 r2 = *(const ushort4*)(ymp + z * PSM + (size_t)n * 400 + 200 + j4);
        s.x += s2.x; s.y += s2.y; s.z += s2.z; s.w += s2.w;
        m.x += b2f(m2.x); m.y += b2f(m2.y); m.z += b2f(m2.z); m.w += b2f(m2.w);
        r.x += b2f(r2.x); r.y += b2f(r2.y); r.z += b2f(r2.z); r.w += b2f(r2.w);
    }
    *(float4*)(y_self + (size_t)n * 200 + j4) = s;
    ushort4 mo, ro;
    mo.x = f2b(m.x); mo.y = f2b(m.y); mo.z = f2b(m.z); mo.w = f2b(m.w);
    ro.x = f2b(r.x); ro.y = f2b(r.y); ro.z = f2b(r.z); ro.w = f2b(r.w);
    *(ushort4*)(y_simb + (size_t)n * 200 + j4) = mo;
    *(ushort4*)(y_ratb + (size_t)n * 200 + j4) = ro;
}

// ---------------- edge sort (counting sort by dst, payload = (src, eid)) -----

__global__ void hist_kernel(const int* __restrict__ e0, const int* __restrict__ e1,
                            int* __restrict__ d0, int* __restrict__ d1)
{
    const int* edges = blockIdx.y ? e1 : e0;
    int* deg = blockIdx.y ? d1 : d0;
    int e = blockIdx.x * 256 + threadIdx.x;
    if (e < EE) atomicAdd(&deg[edges[EE + e]], 1);
}

__global__ void scan_kernel(const int* __restrict__ deg0, int* __restrict__ off0,
                            int* __restrict__ pos0,
                            const int* __restrict__ deg1, int* __restrict__ off1,
                            int* __restrict__ pos1)
{
    const int* deg = blockIdx.x ? deg1 : deg0;
    int* off = blockIdx.x ? off1 : off0;
    int* pos = blockIdx.x ? pos1 : pos0;
    __shared__ int part[256];
    const int t = threadIdx.x;
    const int base = t * 32;
    int s = 0;
#pragma unroll
    for (int i = 0; i < 32; ++i) s += deg[base + i];
    part[t] = s;
    __syncthreads();
    for (int d = 1; d < 256; d <<= 1) {
        int v = (t >= d) ? part[t - d] : 0;
        __syncthreads();
        part[t] += v;
        __syncthreads();
    }
    int run = (t == 0) ? 0 : part[t - 1];
    for (int i = 0; i < 32; ++i) {
        off[base + i] = run;
        pos[base + i] = run;
        run += deg[base + i];
    }
    if (t == 255) off[NN] = run;
}

__global__ void reorder_kernel(const int* __restrict__ e0, int* __restrict__ pos0,
                               int2* __restrict__ se0,
                               const int* __restrict__ e1, int* __restrict__ pos1,
                               int2* __restrict__ se1)
{
    const int* edges = blockIdx.y ? e1 : e0;
    int* pos = blockIdx.y ? pos1 : pos0;
    int2* se = blockIdx.y ? se1 : se0;
    int e = blockIdx.x * 256 + threadIdx.x;
    if (e >= EE) return;
    int p = atomicAdd(&pos[edges[EE + e]], 1);
    se[p] = make_int2(edges[e], e);
}

// ---------------- fused aggregation --------------------------------------

__device__ __forceinline__ void edge_accum(
    const unsigned short* __restrict__ msg,
    const int* __restrict__ off, const int2* __restrict__ se,
    int n, int w, int j4, bool act, float4& acc)
{
    const int e1 = off[n + 1];
    int i = off[n] + w;
    // 4 independent se loads, then 4 independent gathers: latency amortized 4x
    for (; i + 12 < e1; i += 16) {
        const int s0 = se[i].x;
        const int s1 = se[i + 4].x;
        const int s2 = se[i + 8].x;
        const int s3 = se[i + 12].x;
        if (act) {
            ushort4 v0 = *(const ushort4*)(msg + (size_t)s0 * 200 + j4);
            ushort4 v1 = *(const ushort4*)(msg + (size_t)s1 * 200 + j4);
            ushort4 v2 = *(const ushort4*)(msg + (size_t)s2 * 200 + j4);
            ushort4 v3 = *(const ushort4*)(msg + (size_t)s3 * 200 + j4);
            acc.x += (b2f(v0.x) + b2f(v1.x)) + (b2f(v2.x) + b2f(v3.x));
            acc.y += (b2f(v0.y) + b2f(v1.y)) + (b2f(v2.y) + b2f(v3.y));
            acc.z += (b2f(v0.z) + b2f(v1.z)) + (b2f(v2.z) + b2f(v3.z));
            acc.w += (b2f(v0.w) + b2f(v1.w)) + (b2f(v2.w) + b2f(v3.w));
        }
    }
    for (; i < e1; i += 4) {
        const int s = se[i].x;
        if (act) {
            ushort4 v = *(const ushort4*)(msg + (size_t)s * 200 + j4);
            acc.x += b2f(v.x); acc.y += b2f(v.y);
            acc.z += b2f(v.z); acc.w += b2f(v.w);
        }
    }
}

__global__ __launch_bounds__(256) void agg_fused_kernel(
    const unsigned short* __restrict__ msg_sim,
    const unsigned short* __restrict__ msg_rat,
    const int* __restrict__ off_sim, const int2* __restrict__ se_sim,
    const int* __restrict__ off_rat, const int2* __restrict__ se_rat,
    const float* __restrict__ y_self, const float* __restrict__ bias,
    unsigned short* __restrict__ hb, int relu)
{
    __shared__ float part[4][200];
    const int n = blockIdx.x;
    const int w = threadIdx.x >> 6;
    const int lane = threadIdx.x & 63;
    const int j4 = lane << 2;
    const bool act = lane < 50;

    float4 acc = {0.f, 0.f, 0.f, 0.f};
    edge_accum(msg_sim, off_sim, se_sim, n, w, j4, act, acc);
    edge_accum(msg_rat, off_rat, se_rat, n, w, j4, act, acc);

    if (act) *(float4*)&part[w][j4] = acc;
    __syncthreads();
    const int j = threadIdx.x;
    if (j < 200) {
        float v = part[0][j] + part[1][j] + part[2][j] + part[3][j]
                + y_self[(size_t)n * 200 + j] + bias[j];
        if (relu) v = fmaxf(v, 0.f);
        hb[((size_t)n << 8) + j] = f2b(v);
    } else if (j < HPAD) {
        hb[((size_t)n << 8) + j] = 0;     // zero the pad (ws is poisoned)
    }
}

// ---------------- decoder: dst-grouped, hQ gathered from L2-resident array ---
__global__ __launch_bounds__(256) void pred_kernel(
    const unsigned short* __restrict__ hQb,  // [8192, HPAD] bf16
    const unsigned short* __restrict__ h2b,  // [8192, HPAD] bf16
    const int* __restrict__ off, const int2* __restrict__ se,
    const int* __restrict__ mask, float* __restrict__ out)
{
    const int n = blockIdx.x;
    const int w = threadIdx.x >> 6;
    const int lane = threadIdx.x & 63;
    float4 b = {0.f, 0.f, 0.f, 0.f};
    if (lane < 50) {
        ushort4 v = *(const ushort4*)(h2b + ((size_t)n << 8) + (lane << 2));
        b.x = b2f(v.x); b.y = b2f(v.y); b.z = b2f(v.z); b.w = b2f(v.w);
    }
    const int e1 = off[n + 1];
    int i = off[n] + w;
    for (; i + 12 < e1; i += 16) {
        const int2 p0 = se[i];
        const int2 p1 = se[i + 4];
        const int2 p2 = se[i + 8];
        const int2 p3 = se[i + 12];
        float s0 = 0.f, s1 = 0.f, s2 = 0.f, s3 = 0.f;
        if (lane < 50) {
            ushort4 a0 = *(const ushort4*)(hQb + ((size_t)p0.x << 8) + (lane << 2));
            ushort4 a1 = *(const ushort4*)(hQb + ((size_t)p1.x << 8) + (lane << 2));
            ushort4 a2 = *(const ushort4*)(hQb + ((size_t)p2.x << 8) + (lane << 2));
            ushort4 a3 = *(const ushort4*)(hQb + ((size_t)p3.x << 8) + (lane << 2));
            s0 = fmaf(b2f(a0.x), b.x, fmaf(b2f(a0.y), b.y,
                 fmaf(b2f(a0.z), b.z, b2f(a0.w) * b.w)));
            s1 = fmaf(b2f(a1.x), b.x, fmaf(b2f(a1.y), b.y,
                 fmaf(b2f(a1.z), b.z, b2f(a1.w) * b.w)));
            s2 = fmaf(b2f(a2.x), b.x, fmaf(b2f(a2.y), b.y,
                 fmaf(b2f(a2.z), b.z, b2f(a2.w) * b.w)));
            s3 = fmaf(b2f(a3.x), b.x, fmaf(b2f(a3.y), b.y,
                 fmaf(b2f(a3.z), b.z, b2f(a3.w) * b.w)));
        }
#pragma unroll
        for (int o = 32; o > 0; o >>= 1) {    // 4 independent reduce chains
            s0 += __shfl_down(s0, o, 64);
            s1 += __shfl_down(s1, o, 64);
            s2 += __shfl_down(s2, o, 64);
            s3 += __shfl_down(s3, o, 64);
        }
        if (lane == 0) {
            out[p0.y] = mask[p0.y] ? (s0 + 3.5f) : 0.f;
            out[p1.y] = mask[p1.y] ? (s1 + 3.5f) : 0.f;
            out[p2.y] = mask[p2.y] ? (s2 + 3.5f) : 0.f;
            out[p3.y] = mask[p3.y] ? (s3 + 3.5f) : 0.f;
        }
    }
    for (; i < e1; i += 4) {
        const int2 p = se[i];
        float s = 0.f;
        if (lane < 50) {
            ushort4 a = *(const ushort4*)(hQb + ((size_t)p.x << 8) + (lane << 2));
            s = fmaf(b2f(a.x), b.x, fmaf(b2f(a.y), b.y,
                fmaf(b2f(a.z), b.z, b2f(a.w) * b.w)));
        }
#pragma unroll
        for (int o = 32; o > 0; o >>= 1) s += __shfl_down(s, o, 64);
        if (lane == 0) out[p.y] = mask[p.y] ? (s + 3.5f) : 0.f;
    }
}

// ---------------- launch ----------------
extern "C" void kernel_launch(void* const* d_in, const int* in_sizes, int n_in,
                              void* d_out, int out_size, void* d_ws, size_t ws_size,
                              hipStream_t stream)
{
    const float* x       = (const float*)d_in[0];
    const int*   e_sim   = (const int*)d_in[1];
    const int*   e_rat   = (const int*)d_in[2];
    const int*   mask    = (const int*)d_in[3];
    const float* w1_self = (const float*)d_in[4];
    const float* w1_sim  = (const float*)d_in[5];
    const float* w1_rat  = (const float*)d_in[6];
    const float* b1      = (const float*)d_in[7];
    const float* w2_self = (const float*)d_in[8];
    const float* w2_sim  = (const float*)d_in[9];
    const float* w2_rat  = (const float*)d_in[10];
    const float* b2      = (const float*)d_in[11];
    const float* Q       = (const float*)d_in[12];
    float* out = (float*)d_out;

    char* p = (char*)d_ws;
    auto alloc = [&](size_t bytes) -> char* {
        char* r = p;
        p += (bytes + 255) & ~(size_t)255;
        return r;
    };
    unsigned short* wbT1  = (unsigned short*)alloc((size_t)NP * NN * 2);   // 10.5 MB
    unsigned short* wbT2  = (unsigned short*)alloc((size_t)NP * HPAD * 2);
    unsigned short* QT    = (unsigned short*)alloc((size_t)HPAD * HPAD * 2);
    float* ypart_s = (float*)alloc(4 * PSS * 4);                           // 26 MB
    unsigned short* ypart_m = (unsigned short*)alloc(4 * PSM * 2);         // 26 MB
    float* y_self = (float*)alloc((size_t)NN * 200 * 4);                   // 6.6 MB
    unsigned short* y_simb = (unsigned short*)alloc((size_t)NN * 200 * 2); // 3.28 MB
    unsigned short* y_ratb = (unsigned short*)alloc((size_t)NN * 200 * 2); // 3.28 MB
    unsigned short* h1b = (unsigned short*)alloc((size_t)NN * HPAD * 2);
    unsigned short* h2b = (unsigned short*)alloc((size_t)NN * HPAD * 2);
    unsigned short* hQb = (unsigned short*)alloc((size_t)NN * HPAD * 2);
    int* deg_sim = (int*)alloc(NN * 4);
    int* deg_rat = (int*)alloc(NN * 4);
    int* off_sim = (int*)alloc((NN + 1) * 4);
    int* off_rat = (int*)alloc((NN + 1) * 4);
    int* pos_sim = (int*)alloc(NN * 4);
    int* pos_rat = (int*)alloc(NN * 4);
    int2* se_sim = (int2*)alloc((size_t)EE * 8);
    int2* se_rat = (int2*)alloc((size_t)EE * 8);

    const dim3 blk(256);
    const dim3 tblk(32, 8);

    // weight transposes (one batched dispatch; z=0 needs the full k-grid,
    // z=1/2 early-out above kb>=HPAD)
    transpose_w_kernel<<<dim3(NN / 32, NP / 32, 3), tblk, 0, stream>>>(
        w1_self, w1_sim, w1_rat, w2_self, w2_sim, w2_rat, Q, wbT1, wbT2, QT);

    // edge sorts (dst-grouped, payload (src,eid)), both types batched
    hipMemsetAsync(deg_sim, 0, 2 * NN * 4, stream);   // deg_sim+deg_rat contiguous
    hist_kernel<<<dim3(EE / 256, 2), blk, 0, stream>>>(e_sim, e_rat, deg_sim, deg_rat);
    scan_kernel<<<2, blk, 0, stream>>>(deg_sim, off_sim, pos_sim,
                                       deg_rat, off_rat, pos_rat);
    reorder_kernel<<<dim3(EE / 256, 2), blk, 0, stream>>>(
        e_sim, pos_sim, se_sim, e_rat, pos_rat, se_rat);

    // layer 1 (split-K = 4; fused f32->bf16 A-staging reads x directly)
    gemm_mfma<1><<<dim3(NP / 128, NN / 128, 4), blk, 0, stream>>>(
        x, wbT1, NN, NN / 4, nullptr, 0,
        nullptr, nullptr, nullptr, ypart_s, ypart_m);
    combine_kernel<<<NN * 50 / 256, blk, 0, stream>>>(
        ypart_s, ypart_m, y_self, y_simb, y_ratb);
    agg_fused_kernel<<<NN, blk, 0, stream>>>(
        y_simb, y_ratb, off_sim, se_sim, off_rat, se_rat, y_self, b1, h1b, 1);

    // layer 2 (combine fused into GEMM epilogue: no ypart roundtrip)
    gemm_mfma<0><<<dim3(NP / 128, NN / 128, 1), blk, 0, stream>>>(
        h1b, wbT2, HPAD, HPAD, nullptr, 0,
        y_self, y_simb, y_ratb, nullptr, nullptr);
    agg_fused_kernel<<<NN, blk, 0, stream>>>(
        y_simb, y_ratb, off_sim, se_sim, off_rat, se_rat, y_self, b2, h2b, 0);

    // decoder (GEMM emits bf16 directly into hQb)
    gemm_mfma<0><<<dim3(HPAD / 128, NN / 128, 1), blk, 0, stream>>>(
        h2b, QT, HPAD, HPAD, hQb, HPAD,
        nullptr, nullptr, nullptr, nullptr, nullptr);
    pred_kernel<<<NN, blk, 0, stream>>>(hQb, h2b, off_rat, se_rat, mask, out);
}